// Round 5
// baseline (1396.881 us; speedup 1.0000x reference)
//
#include <hip/hip_runtime.h>
#include <hip/hip_bf16.h>
#include <math.h>

constexpr int NA  = 100000;
constexpr int NPP = 100000;
constexpr int D   = 128;
constexpr int H   = 4;
constexpr int E   = 400000;
constexpr int R   = 3;
constexpr int L   = 2;
constexpr int NSLOT = 23;
constexpr int SLOT_ELEMS = 8 * 4 * 512;   // 8 col-tiles * 4 ksteps * 512 bf16

using s8v = __attribute__((ext_vector_type(8))) short;
using f4v = __attribute__((ext_vector_type(4))) float;

static __device__ __forceinline__ unsigned short f2bf(float f) {
  unsigned u = __float_as_uint(f);
  return (unsigned short)((u + 0x7fffu + ((u >> 16) & 1u)) >> 16);
}
static __device__ __forceinline__ float bf2f(unsigned short s) {
  return __uint_as_float(((unsigned)s) << 16);
}
static __device__ __forceinline__ float gelu_f(float x) {
  return 0.5f * x * (1.0f + erff(x * 0.70710678118654752f));
}
static __device__ __forceinline__ float elu_f(float x) {
  return x > 0.0f ? x : expm1f(x);
}

// =============== MFMA GEMM v4: C = act(A[M,128]) @ B + bias (bf16x3 split) ======
// block = 256 thr = 4 waves; wave computes 16 rows x NT16*16 cols.
// A fragment: lane l -> row = l&15, k(i) = 4*(l>>4) + (i&3) + 16*(i>>2) + 32*ks.
// B packed by pack_b in the SAME k-order -> any hw k-permutation cancels.
// C/D layout (m89-verified): col = lane&15, row = (lane>>4)*4 + reg.
// STORE: 0 = fp32 plain, 1 = bf16 plain,
//        2 = kv pair-interleaved [k0,v0,k1,v1,...] (NT16=16: K tiles 0-7, V 8-15;
//            packed k/v weight slots are adjacent so ct indexes across both;
//            epilogue writes ushort2 {k,v} -> coalesced dword stores).
template<int NT16, int NCOLS, int STORE, bool GELU_A, bool MIX>
__global__ __launch_bounds__(256, 4) void gemm3(
    const float* __restrict__ A,
    const unsigned short* __restrict__ Bhi, const unsigned short* __restrict__ Blo,
    const float* __restrict__ bias, void* __restrict__ Cv,
    const float* __restrict__ skip_ptr, int M) {
  const int lane = threadIdx.x & 63;
  const int wave = threadIdx.x >> 6;
  const int row0 = blockIdx.x * 64 + wave * 16;
  const int g = lane >> 4, li = lane & 15;

  f4v acc[NT16];
#pragma unroll
  for (int ct = 0; ct < NT16; ++ct) acc[ct] = f4v{0.f, 0.f, 0.f, 0.f};

  int arow = row0 + li;
  if (arow >= M) arow = M - 1;             // clamp (stores guarded)
  const float* ap = A + (size_t)arow * 128 + g * 4;

#pragma unroll
  for (int ks = 0; ks < 4; ++ks) {
    float4 u0 = *(const float4*)(ap + ks * 32);
    float4 u1 = *(const float4*)(ap + ks * 32 + 16);
    float x[8] = {u0.x, u0.y, u0.z, u0.w, u1.x, u1.y, u1.z, u1.w};
    s8v ahi, alo;
#pragma unroll
    for (int i = 0; i < 8; ++i) {
      float v = GELU_A ? gelu_f(x[i]) : x[i];
      unsigned short h = f2bf(v);
      ahi[i] = (short)h;
      alo[i] = (short)f2bf(v - bf2f(h));
    }
#pragma unroll
    for (int ct = 0; ct < NT16; ++ct) {
      size_t boff = (size_t)((ct * 4 + ks) << 9) + (lane << 3);
      s8v bhi = *(const s8v*)(Bhi + boff);
      s8v blo = *(const s8v*)(Blo + boff);
      acc[ct] = __builtin_amdgcn_mfma_f32_16x16x32_bf16(ahi, bhi, acc[ct], 0, 0, 0);
      acc[ct] = __builtin_amdgcn_mfma_f32_16x16x32_bf16(alo, bhi, acc[ct], 0, 0, 0);
      acc[ct] = __builtin_amdgcn_mfma_f32_16x16x32_bf16(ahi, blo, acc[ct], 0, 0, 0);
    }
  }

  float sskip = 0.f;
  if (MIX) sskip = 1.f / (1.f + __expf(-*skip_ptr));

  if constexpr (STORE == 2) {
    // K in acc[0..7], V in acc[8..15]; same col c = ct*16+li in one lane.
#pragma unroll
    for (int ct = 0; ct < 8; ++ct) {
      int col = ct * 16 + li;
      float bk = bias[col], bv = bias[128 + col];
#pragma unroll
      for (int r = 0; r < 4; ++r) {
        int grow = row0 + g * 4 + r;
        if (grow < M) {
          ushort2 o;
          o.x = f2bf(acc[ct][r] + bk);
          o.y = f2bf(acc[ct + 8][r] + bv);
          *(ushort2*)((unsigned short*)Cv + (size_t)grow * 256 + 2 * col) = o;
        }
      }
    }
  } else {
#pragma unroll
    for (int ct = 0; ct < NT16; ++ct) {
      int col = ct * 16 + li;
      bool colok = (col < NCOLS);
      float bv = colok ? bias[col] : 0.f;
#pragma unroll
      for (int r = 0; r < 4; ++r) {
        int grow = row0 + g * 4 + r;
        if (grow < M && colok) {
          float v = acc[ct][r] + bv;
          if constexpr (MIX) {
            float* Cp = (float*)Cv;
            size_t off = (size_t)grow * NCOLS + col;
            float hprev = Cp[off];
            Cp[off] = elu_f(sskip * v + (1.f - sskip) * hprev);
          } else if constexpr (STORE == 1) {
            ((unsigned short*)Cv)[(size_t)grow * NCOLS + col] = f2bf(v);
          } else {
            ((float*)Cv)[(size_t)grow * NCOLS + col] = v;
          }
        }
      }
    }
  }
}

// ------------- combined weights: cw = W @ blockdiag(rel), cb = b @ blockdiag(rel)
__global__ __launch_bounds__(256) void combine_w(
    const float* __restrict__ kqv_w, const float* __restrict__ kqv_b,
    const float* __restrict__ rel_a, const float* __restrict__ rel_m,
    float* __restrict__ cw, float* __restrict__ cb) {
  int b  = blockIdx.x;            // ((l*R)+r)*2+kv
  int kv = b & 1;
  int r  = (b >> 1) % R;
  int l  = b / (2 * R);
  int t_src = (r == 0) ? 0 : 1;
  int i_w   = (kv == 0) ? 0 : 2;
  const float* W    = kqv_w + ((size_t)((l*3 + i_w)*2 + t_src)) * D * D;
  const float* bvec = kqv_b + ((size_t)((l*3 + i_w)*2 + t_src)) * D;
  const float* rel  = ((kv == 0) ? rel_a : rel_m) + ((size_t)(l*R + r)) * H * 32 * 32;
  float* Cout = cw + (size_t)b * D * D;
  float* cbo  = cb + (size_t)b * D;
  for (int idx = threadIdx.x; idx < D * D; idx += 256) {
    int i = idx / D, j = idx % D;
    int h = j >> 5, f = j & 31;
    const float* relh = rel + h * 32 * 32;
    float sum = 0.f;
#pragma unroll
    for (int d = 0; d < 32; ++d) sum += W[i*D + (h*32 + d)] * relh[d*32 + f];
    Cout[idx] = sum;
  }
  if (threadIdx.x < D) {
    int j = threadIdx.x;
    int h = j >> 5, f = j & 31;
    const float* relh = rel + h * 32 * 32;
    float sum = 0.f;
#pragma unroll
    for (int d = 0; d < 32; ++d) sum += bvec[h*32 + d] * relh[d*32 + f];
    cbo[j] = sum;
  }
}

// ------------- pack weight matrices into MFMA-fragment order (hi/lo split) -------
__global__ __launch_bounds__(256) void pack_b(
    const float* __restrict__ proj_w, const float* __restrict__ kqv_w,
    const float* __restrict__ out_w, const float* __restrict__ cls_w,
    const float* __restrict__ cw,
    unsigned short* __restrict__ phi, unsigned short* __restrict__ plo) {
  int slot = blockIdx.x;
  const float* src; int ncol = 128;
  if (slot == 0) src = proj_w;
  else if (slot == 1) src = proj_w + D * D;
  else if (slot == 22) { src = cls_w; ncol = 40; }
  else {
    int l = (slot - 2) / 10, k = (slot - 2) % 10;
    if (k == 0)      src = kqv_w + ((size_t)((l*3 + 1)*2 + 0)) * D * D;
    else if (k == 1) src = kqv_w + ((size_t)((l*3 + 1)*2 + 1)) * D * D;
    else if (k < 8)  { int idx = k - 2; src = cw + ((size_t)((l*R)*2 + idx)) * D * D; }
    else             src = out_w + ((size_t)(l*2 + (k - 8))) * D * D;
  }
  int nt = (ncol + 15) / 16;
  int total = nt * 4 * 512;
  unsigned short* ph = phi + (size_t)slot * SLOT_ELEMS;
  unsigned short* pl = plo + (size_t)slot * SLOT_ELEMS;
  for (int idx = threadIdx.x; idx < total; idx += 256) {
    int j = idx & 7, lane = (idx >> 3) & 63, ks = (idx >> 9) & 3, ct = idx >> 11;
    int k = 4 * (lane >> 4) + (j & 3) + 16 * (j >> 2) + 32 * ks;
    int n = ct * 16 + (lane & 15);
    float v = (n < ncol) ? src[(size_t)k * ncol + n] : 0.f;
    unsigned short h = f2bf(v);
    ph[idx] = h;
    pl[idx] = f2bf(v - bf2f(h));
  }
}

// ---------------- CSR build ----------------
__global__ void count3(const int* __restrict__ ei_w, const int* __restrict__ ei_c,
                       const int* __restrict__ ei_r, int* __restrict__ degz) {
  const int* dst = blockIdx.y == 0 ? ei_w + E : blockIdx.y == 1 ? ei_c + E : ei_r + E;
  int* deg = degz + blockIdx.y * NPP;
  for (int e = blockIdx.x * blockDim.x + threadIdx.x; e < E; e += gridDim.x * blockDim.x)
    atomicAdd(&deg[dst[e]], 1);
}
__global__ void fill3(const int* __restrict__ ei_w, const int* __restrict__ ei_c,
                      const int* __restrict__ ei_r,
                      const int* __restrict__ rp_w, const int* __restrict__ rp_c,
                      const int* __restrict__ rp_r,
                      int* __restrict__ cntz, int* __restrict__ colz) {
  int rel = blockIdx.y;
  const int* ei = rel == 0 ? ei_w : rel == 1 ? ei_c : ei_r;
  const int* dst = ei + E;
  const int* rp  = rel == 0 ? rp_w : rel == 1 ? rp_c : rp_r;
  int* cnt = cntz + rel * NPP;
  int* col = colz + rel * E;
  for (int e = blockIdx.x * blockDim.x + threadIdx.x; e < E; e += gridDim.x * blockDim.x) {
    int d = dst[e];
    int pos = atomicAdd(&cnt[d], 1);
    col[rp[d] + pos] = ei[e];          // store SOURCE node directly
  }
}

// 3-phase exclusive scan over three 100000-length deg arrays (contiguous)
__global__ __launch_bounds__(256) void scan_partial(const int* __restrict__ degz,
                                                    int* __restrict__ bsum) {
  int blk = blockIdx.x, rel = blk / 25, t25 = blk % 25;
  const int* deg = degz + rel * NPP + t25 * 4096;
  int nrem = min(4096, NPP - t25 * 4096);
  int base = threadIdx.x * 16;
  int s = 0;
  if (base < nrem) {
#pragma unroll
    for (int i4 = 0; i4 < 4; ++i4) {
      int4 v = *(const int4*)(deg + base + i4 * 4);
      s += v.x + v.y + v.z + v.w;
    }
  }
  __shared__ int sm[256];
  sm[threadIdx.x] = s; __syncthreads();
  for (int o = 128; o > 0; o >>= 1) {
    if (threadIdx.x < o) sm[threadIdx.x] += sm[threadIdx.x + o];
    __syncthreads();
  }
  if (threadIdx.x == 0) bsum[blk] = sm[0];
}
__global__ __launch_bounds__(128) void scan_offsets(const int* __restrict__ bsum,
                                                    int* __restrict__ boff,
                                                    int* rp_w, int* rp_c, int* rp_r) {
  __shared__ int sm[128];
  int t = threadIdx.x;
  sm[t] = (t < 75) ? bsum[t] : 0;
  __syncthreads();
  for (int o = 1; o < 128; o <<= 1) {
    int v = (t >= o) ? sm[t - o] : 0;
    __syncthreads(); sm[t] += v; __syncthreads();
  }
  if (t < 75) {
    int rel = t / 25;
    int base = rel ? sm[rel * 25 - 1] : 0;
    boff[t] = (t % 25 == 0) ? 0 : (sm[t - 1] - base);
    if (t % 25 == 24) {
      int total = sm[t] - base;
      if (rel == 0) rp_w[NPP] = total;
      else if (rel == 1) rp_c[NPP] = total;
      else rp_r[NA] = total;
    }
  }
}
__global__ __launch_bounds__(256) void scan_final(const int* __restrict__ degz,
                                                  const int* __restrict__ boff,
                                                  int* rp_w, int* rp_c, int* rp_r) {
  int blk = blockIdx.x, rel = blk / 25, t25 = blk % 25;
  const int* deg = degz + rel * NPP + t25 * 4096;
  int* rp = (rel == 0 ? rp_w : rel == 1 ? rp_c : rp_r) + t25 * 4096;
  int nrem = min(4096, NPP - t25 * 4096);
  int base = threadIdx.x * 16;
  bool ok = base < nrem;
  int v[16]; int s = 0;
  if (ok) {
#pragma unroll
    for (int i4 = 0; i4 < 4; ++i4) {
      int4 u = *(const int4*)(deg + base + i4 * 4);
      v[i4*4+0] = u.x; v[i4*4+1] = u.y; v[i4*4+2] = u.z; v[i4*4+3] = u.w;
      s += u.x + u.y + u.z + u.w;
    }
  }
  __shared__ int sm[256];
  sm[threadIdx.x] = s; __syncthreads();
  for (int o = 1; o < 256; o <<= 1) {
    int x = (threadIdx.x >= o) ? sm[threadIdx.x - o] : 0;
    __syncthreads(); sm[threadIdx.x] += x; __syncthreads();
  }
  int run = boff[blk] + sm[threadIdx.x] - s;
  if (ok) {
    int w[16];
#pragma unroll
    for (int i = 0; i < 16; ++i) { w[i] = run; run += v[i]; }
#pragma unroll
    for (int i4 = 0; i4 < 4; ++i4) *(int4*)(rp + base + i4 * 4) = *(const int4*)&w[i4*4];
  }
}

// -------- per-destination attention (no-max softmax: scores are O(1)) -----------
// 1 wave / node; lane holds dims {2l, 2l+1}; head = lane>>4; one ushort4 gather
// per edge from the pair-interleaved kv buffer [k0,v0,k1,v1,...]:
//   u.x=k_{2l}, u.y=v_{2l}, u.z=k_{2l+1}, u.w=v_{2l+1}
template<int FIRST, int LAST>
__global__ __launch_bounds__(256, 8) void attn3(
    const int* __restrict__ rp, const int* __restrict__ col,
    const unsigned short* __restrict__ q, const unsigned short* __restrict__ kv,
    const float* __restrict__ prel, int ndst,
    float* __restrict__ z_st, float* __restrict__ acc) {
  int dst  = blockIdx.x * 4 + (threadIdx.x >> 6);
  int lane = threadIdx.x & 63;
  if (dst >= ndst) return;
  int head = lane >> 4;
  const float scale = 0.17677669529663688f; // 1/sqrt(32)
  float pr = prel[head] * scale;
  ushort2 qv = *(const ushort2*)(q + (size_t)dst * D + lane * 2);
  float qx = bf2f(qv.x), qy = bf2f(qv.y);
  float z, ax, ay;
  if (FIRST) { z = 0.f; ax = 0.f; ay = 0.f; }
  else {
    z = z_st[dst * H + head];
    float2 a = *(float2*)(acc + (size_t)dst * D + lane * 2);
    ax = a.x; ay = a.y;
  }
  int e0 = rp[dst], e1 = rp[dst + 1];
  int j = e0;
  for (; j + 1 < e1; j += 2) {
    int s0 = col[j], s1 = col[j + 1];
    ushort4 u = *(const ushort4*)(kv + (size_t)s0 * 256 + lane * 4);
    ushort4 w = *(const ushort4*)(kv + (size_t)s1 * 256 + lane * 4);
    float p0 = qx * bf2f(u.x) + qy * bf2f(u.z);
    float p1 = qx * bf2f(w.x) + qy * bf2f(w.z);
    p0 += __shfl_xor(p0, 1); p1 += __shfl_xor(p1, 1);
    p0 += __shfl_xor(p0, 2); p1 += __shfl_xor(p1, 2);
    p0 += __shfl_xor(p0, 4); p1 += __shfl_xor(p1, 4);
    p0 += __shfl_xor(p0, 8); p1 += __shfl_xor(p1, 8);
    float ea = __expf(p0 * pr);
    float eb = __expf(p1 * pr);
    z  += ea + eb;
    ax += ea * bf2f(u.y) + eb * bf2f(w.y);
    ay += ea * bf2f(u.w) + eb * bf2f(w.w);
  }
  if (j < e1) {
    int s0 = col[j];
    ushort4 u = *(const ushort4*)(kv + (size_t)s0 * 256 + lane * 4);
    float p0 = qx * bf2f(u.x) + qy * bf2f(u.z);
    p0 += __shfl_xor(p0, 1);
    p0 += __shfl_xor(p0, 2);
    p0 += __shfl_xor(p0, 4);
    p0 += __shfl_xor(p0, 8);
    float ea = __expf(p0 * pr);
    z  += ea;
    ax += ea * bf2f(u.y);
    ay += ea * bf2f(u.w);
  }
  if (LAST) {
    float inv = 1.f / (z + 1e-16f);
    *(float2*)(acc + (size_t)dst * D + lane * 2) = make_float2(ax * inv, ay * inv);
  } else {
    *(float2*)(acc + (size_t)dst * D + lane * 2) = make_float2(ax, ay);
    if ((lane & 15) == 0) z_st[dst * H + head] = z;
  }
}

extern "C" void kernel_launch(void* const* d_in, const int* in_sizes, int n_in,
                              void* d_out, int out_size, void* d_ws, size_t ws_size,
                              hipStream_t stream) {
  const float* x_a    = (const float*)d_in[0];
  const float* x_p    = (const float*)d_in[1];
  const int*   ei_w   = (const int*)d_in[2];
  const int*   ei_r   = (const int*)d_in[3];
  const int*   ei_c   = (const int*)d_in[4];
  const float* proj_w = (const float*)d_in[5];
  const float* proj_b = (const float*)d_in[6];
  const float* kqv_w  = (const float*)d_in[7];
  const float* kqv_b  = (const float*)d_in[8];
  const float* out_w  = (const float*)d_in[9];
  const float* out_b  = (const float*)d_in[10];
  const float* rel_a  = (const float*)d_in[11];
  const float* rel_m  = (const float*)d_in[12];
  const float* p_rel  = (const float*)d_in[13];
  const float* skip   = (const float*)d_in[14];
  const float* cls_w  = (const float*)d_in[15];
  const float* cls_b  = (const float*)d_in[16];
  float* out = (float*)d_out;

  const size_t NF = (size_t)NA * D;   // 12.8M
  float* ws    = (float*)d_ws;
  float* h_a   = ws;
  float* h_p   = h_a + NF;
  float* b_acc = h_p + NF;
  unsigned short* b_q  = (unsigned short*)(b_acc + NF);   // NF
  unsigned short* b_kv = b_q + NF;                        // 2*NF pair-interleaved k/v
  float* cw    = (float*)(b_kv + 2 * NF);       // 12*D*D
  float* cb    = cw + 12 * D * D;               // 12*D
  float* z_st  = cb + 12 * D;                   // NPP*H
  unsigned short* phi = (unsigned short*)(z_st + (size_t)NPP * H);  // 23*SLOT_ELEMS
  unsigned short* plo = phi + (size_t)NSLOT * SLOT_ELEMS;
  int* ip    = (int*)(plo + (size_t)NSLOT * SLOT_ELEMS);
  int* rp_w  = ip;                      // NPP+1
  int* rp_c  = rp_w + (NPP + 1);
  int* rp_r  = rp_c + (NPP + 1);
  int* degz  = rp_r + (NA + 1);         // 3*NPP deg + 3*NPP cnt (contiguous)
  int* cntz  = degz + 3 * NPP;
  int* colz  = cntz + 3 * NPP;          // 3*E (src-node per CSR entry)
  int* bsum  = colz + 3 * E;            // 75
  int* boff  = bsum + 128;              // 75
  size_t need_bytes = (size_t)((char*)(boff + 128) - (char*)d_ws);
  if (ws_size < need_bytes) return;

  hipMemsetAsync(degz, 0, sizeof(int) * 6 * (size_t)NPP, stream);

  count3<<<dim3(256, 3), 256, 0, stream>>>(ei_w, ei_c, ei_r, degz);
  scan_partial<<<75, 256, 0, stream>>>(degz, bsum);
  scan_offsets<<<1, 128, 0, stream>>>(bsum, boff, rp_w, rp_c, rp_r);
  scan_final<<<75, 256, 0, stream>>>(degz, boff, rp_w, rp_c, rp_r);
  fill3<<<dim3(256, 3), 256, 0, stream>>>(ei_w, ei_c, ei_r, rp_w, rp_c, rp_r, cntz, colz);
  int* col_w = colz;
  int* col_c = colz + E;
  int* col_r = colz + 2 * E;

  combine_w<<<12, 256, 0, stream>>>(kqv_w, kqv_b, rel_a, rel_m, cw, cb);
  pack_b<<<NSLOT, 256, 0, stream>>>(proj_w, kqv_w, out_w, cls_w, cw, phi, plo);

  auto PH = [&](int s){ return phi + (size_t)s * SLOT_ELEMS; };
  auto PL = [&](int s){ return plo + (size_t)s * SLOT_ELEMS; };

  const int GB = (NA + 63) / 64;       // 1563
  const dim3 G1(GB, 1);
  // initial projections (fp32 out)
  gemm3<8, 128, 0, false, false><<<G1, 256, 0, stream>>>(
      x_a, PH(0), PL(0), proj_b,     h_a, nullptr, NA);
  gemm3<8, 128, 0, false, false><<<G1, 256, 0, stream>>>(
      x_p, PH(1), PL(1), proj_b + D, h_p, nullptr, NPP);

  for (int l = 0; l < L; ++l) {
    const int SQA = 2 + l * 10 + 0, SQP = 2 + l * 10 + 1;
    auto SKV = [&](int r){ return 2 + l * 10 + 2 + r * 2; };  // k slot; v slot = +1 (adjacent)
    const int SO0 = 2 + l * 10 + 8, SO1 = 2 + l * 10 + 9;
    const float* bq_a = kqv_b + ((size_t)((l*3 + 1)*2 + 0)) * D;
    const float* bq_p = kqv_b + ((size_t)((l*3 + 1)*2 + 1)) * D;
    auto CB2 = [&](int r){ return cb + ((size_t)((l*R + r)*2)) * D; };  // 256 floats (k|v)

    // ---- author destination (rev_writes r=1, src=paper) ----
    gemm3<8, 128, 1, false, false><<<G1, 256, 0, stream>>>(
        h_a, PH(SQA), PL(SQA), bq_a, b_q, nullptr, NA);
    gemm3<16, 128, 2, false, false><<<G1, 256, 0, stream>>>(
        h_p, PH(SKV(1)), PL(SKV(1)), CB2(1), b_kv, nullptr, NPP);
    attn3<1, 1><<<(NA + 3) / 4, 256, 0, stream>>>(
        rp_r, col_r, b_q, b_kv, p_rel + (size_t)(l*R + 1) * H, NA, z_st, b_acc);
    // writes-relation K/V from OLD h_a (before author update)
    gemm3<16, 128, 2, false, false><<<G1, 256, 0, stream>>>(
        h_a, PH(SKV(0)), PL(SKV(0)), CB2(0), b_kv, nullptr, NA);
    // author out-mix (in-place h_a)
    gemm3<8, 128, 0, true, true><<<G1, 256, 0, stream>>>(
        b_acc, PH(SO0), PL(SO0), out_b + (size_t)(l*2 + 0) * D, h_a,
        skip + l*2 + 0, NA);

    // ---- paper destination: joint softmax over writes(r=0) + cites(r=2) ----
    gemm3<8, 128, 1, false, false><<<G1, 256, 0, stream>>>(
        h_p, PH(SQP), PL(SQP), bq_p, b_q, nullptr, NPP);
    attn3<1, 0><<<(NPP + 3) / 4, 256, 0, stream>>>(
        rp_w, col_w, b_q, b_kv, p_rel + (size_t)(l*R + 0) * H, NPP, z_st, b_acc);
    gemm3<16, 128, 2, false, false><<<G1, 256, 0, stream>>>(
        h_p, PH(SKV(2)), PL(SKV(2)), CB2(2), b_kv, nullptr, NPP);
    attn3<0, 1><<<(NPP + 3) / 4, 256, 0, stream>>>(
        rp_c, col_c, b_q, b_kv, p_rel + (size_t)(l*R + 2) * H, NPP, z_st, b_acc);
    gemm3<8, 128, 0, true, true><<<G1, 256, 0, stream>>>(
        b_acc, PH(SO1), PL(SO1), out_b + (size_t)(l*2 + 1) * D, h_p,
        skip + l*2 + 1, NPP);
  }

  gemm3<3, 40, 0, false, false><<<G1, 256, 0, stream>>>(
      h_p, PH(22), PL(22), cls_b, out, nullptr, NPP);
}

// Round 6
// 1367.186 us; speedup vs baseline: 1.0217x; 1.0217x over previous
//
#include <hip/hip_runtime.h>
#include <hip/hip_bf16.h>
#include <math.h>

constexpr int NA  = 100000;
constexpr int NPP = 100000;
constexpr int D   = 128;
constexpr int H   = 4;
constexpr int E   = 400000;
constexpr int R   = 3;
constexpr int L   = 2;
constexpr int NSLOT = 23;
constexpr int SLOT_ELEMS = 8 * 4 * 512;   // 8 col-tiles * 4 ksteps * 512 bf16

using s8v = __attribute__((ext_vector_type(8))) short;
using f4v = __attribute__((ext_vector_type(4))) float;

static __device__ __forceinline__ unsigned short f2bf(float f) {
  unsigned u = __float_as_uint(f);
  return (unsigned short)((u + 0x7fffu + ((u >> 16) & 1u)) >> 16);
}
static __device__ __forceinline__ float bf2f(unsigned short s) {
  return __uint_as_float(((unsigned)s) << 16);
}
static __device__ __forceinline__ float gelu_f(float x) {
  return 0.5f * x * (1.0f + erff(x * 0.70710678118654752f));
}
static __device__ __forceinline__ float elu_f(float x) {
  return x > 0.0f ? x : expm1f(x);
}

// =============== MFMA GEMM: C = act(A[M,128]) @ B + bias (bf16x3 split) =========
// block = 256 thr = 4 waves; wave computes 16 rows x NT16*16 cols. acc = 4*NT16 regs.
// A fragment: lane l -> row = l&15, k(i) = 4*(l>>4) + (i&3) + 16*(i>>2) + 32*ks.
// B packed by pack_b in the SAME k-order -> any hw k-permutation cancels.
// C/D layout (m89-verified): col = lane&15, row = (lane>>4)*4 + reg.
// STORE: 0 = fp32 plain, 1 = bf16 plain.
template<int NT16, int NCOLS, int STORE, bool GELU_A, bool MIX>
__global__ __launch_bounds__(256, 4) void gemm3(
    const float* __restrict__ A,
    const unsigned short* __restrict__ Bhi, const unsigned short* __restrict__ Blo,
    const float* __restrict__ bias, void* __restrict__ Cv,
    const float* __restrict__ skip_ptr, int M) {
  const int lane = threadIdx.x & 63;
  const int wave = threadIdx.x >> 6;
  const int row0 = blockIdx.x * 64 + wave * 16;
  const int g = lane >> 4, li = lane & 15;

  f4v acc[NT16];
#pragma unroll
  for (int ct = 0; ct < NT16; ++ct) acc[ct] = f4v{0.f, 0.f, 0.f, 0.f};

  int arow = row0 + li;
  if (arow >= M) arow = M - 1;             // clamp (stores guarded)
  const float* ap = A + (size_t)arow * 128 + g * 4;

#pragma unroll
  for (int ks = 0; ks < 4; ++ks) {
    float4 u0 = *(const float4*)(ap + ks * 32);
    float4 u1 = *(const float4*)(ap + ks * 32 + 16);
    float x[8] = {u0.x, u0.y, u0.z, u0.w, u1.x, u1.y, u1.z, u1.w};
    s8v ahi, alo;
#pragma unroll
    for (int i = 0; i < 8; ++i) {
      float v = GELU_A ? gelu_f(x[i]) : x[i];
      unsigned short h = f2bf(v);
      ahi[i] = (short)h;
      alo[i] = (short)f2bf(v - bf2f(h));
    }
#pragma unroll
    for (int ct = 0; ct < NT16; ++ct) {
      size_t boff = (size_t)((ct * 4 + ks) << 9) + (lane << 3);
      s8v bhi = *(const s8v*)(Bhi + boff);
      s8v blo = *(const s8v*)(Blo + boff);
      acc[ct] = __builtin_amdgcn_mfma_f32_16x16x32_bf16(ahi, bhi, acc[ct], 0, 0, 0);
      acc[ct] = __builtin_amdgcn_mfma_f32_16x16x32_bf16(alo, bhi, acc[ct], 0, 0, 0);
      acc[ct] = __builtin_amdgcn_mfma_f32_16x16x32_bf16(ahi, blo, acc[ct], 0, 0, 0);
    }
  }

  float sskip = 0.f;
  if (MIX) sskip = 1.f / (1.f + __expf(-*skip_ptr));
#pragma unroll
  for (int ct = 0; ct < NT16; ++ct) {
    int col = ct * 16 + li;
    bool colok = (col < NCOLS);
    float bv = colok ? bias[col] : 0.f;
#pragma unroll
    for (int r = 0; r < 4; ++r) {
      int grow = row0 + g * 4 + r;
      if (grow < M && colok) {
        float v = acc[ct][r] + bv;
        if constexpr (MIX) {
          float* Cp = (float*)Cv;
          size_t off = (size_t)grow * NCOLS + col;
          float hprev = Cp[off];
          Cp[off] = elu_f(sskip * v + (1.f - sskip) * hprev);
        } else if constexpr (STORE == 1) {
          ((unsigned short*)Cv)[(size_t)grow * NCOLS + col] = f2bf(v);
        } else {
          ((float*)Cv)[(size_t)grow * NCOLS + col] = v;
        }
      }
    }
  }
}

// ============ KV GEMM: column-half split, pair-interleaved coalesced store ======
// grid (GB, 2); blockIdx.y = column half. Each block: 4 K-tiles + 4 V-tiles
// (acc = 32 regs, occupancy-friendly). V slot adjacent to K slot (+SLOT_ELEMS).
// Store ushort2{k_c, v_c} at kv[row*256 + 2c] -> y=0 owns bytes [0,256) of each
// row, y=1 owns [256,512): no 64B line shared across blocks/XCDs.
__global__ __launch_bounds__(256, 4) void gemm_kv(
    const float* __restrict__ A,
    const unsigned short* __restrict__ Bhi, const unsigned short* __restrict__ Blo,
    const float* __restrict__ bias, unsigned short* __restrict__ kvout, int M) {
  const int lane = threadIdx.x & 63;
  const int wave = threadIdx.x >> 6;
  const int row0 = blockIdx.x * 64 + wave * 16;
  const int g = lane >> 4, li = lane & 15;
  const int ch = blockIdx.y;

  f4v acc[8];
#pragma unroll
  for (int t = 0; t < 8; ++t) acc[t] = f4v{0.f, 0.f, 0.f, 0.f};

  int arow = row0 + li;
  if (arow >= M) arow = M - 1;
  const float* ap = A + (size_t)arow * 128 + g * 4;

#pragma unroll
  for (int ks = 0; ks < 4; ++ks) {
    float4 u0 = *(const float4*)(ap + ks * 32);
    float4 u1 = *(const float4*)(ap + ks * 32 + 16);
    float x[8] = {u0.x, u0.y, u0.z, u0.w, u1.x, u1.y, u1.z, u1.w};
    s8v ahi, alo;
#pragma unroll
    for (int i = 0; i < 8; ++i) {
      unsigned short h = f2bf(x[i]);
      ahi[i] = (short)h;
      alo[i] = (short)f2bf(x[i] - bf2f(h));
    }
#pragma unroll
    for (int t = 0; t < 4; ++t) {
      int ct = ch * 4 + t;
      size_t bk = (size_t)((ct * 4 + ks) << 9) + (lane << 3);
      s8v kh = *(const s8v*)(Bhi + bk);
      s8v kl = *(const s8v*)(Blo + bk);
      acc[t] = __builtin_amdgcn_mfma_f32_16x16x32_bf16(ahi, kh, acc[t], 0, 0, 0);
      acc[t] = __builtin_amdgcn_mfma_f32_16x16x32_bf16(alo, kh, acc[t], 0, 0, 0);
      acc[t] = __builtin_amdgcn_mfma_f32_16x16x32_bf16(ahi, kl, acc[t], 0, 0, 0);
      size_t bv = (size_t)SLOT_ELEMS + bk;        // V slot adjacent
      s8v vh = *(const s8v*)(Bhi + bv);
      s8v vl = *(const s8v*)(Blo + bv);
      acc[4 + t] = __builtin_amdgcn_mfma_f32_16x16x32_bf16(ahi, vh, acc[4 + t], 0, 0, 0);
      acc[4 + t] = __builtin_amdgcn_mfma_f32_16x16x32_bf16(alo, vh, acc[4 + t], 0, 0, 0);
      acc[4 + t] = __builtin_amdgcn_mfma_f32_16x16x32_bf16(ahi, vl, acc[4 + t], 0, 0, 0);
    }
  }

#pragma unroll
  for (int t = 0; t < 4; ++t) {
    int col = ch * 64 + t * 16 + li;
    float bk = bias[col], bv = bias[128 + col];
#pragma unroll
    for (int r = 0; r < 4; ++r) {
      int grow = row0 + g * 4 + r;
      if (grow < M) {
        ushort2 o;
        o.x = f2bf(acc[t][r] + bk);
        o.y = f2bf(acc[4 + t][r] + bv);
        *(ushort2*)(kvout + (size_t)grow * 256 + 2 * col) = o;
      }
    }
  }
}

// ------------- combined weights: cw = W @ blockdiag(rel), cb = b @ blockdiag(rel)
__global__ __launch_bounds__(256) void combine_w(
    const float* __restrict__ kqv_w, const float* __restrict__ kqv_b,
    const float* __restrict__ rel_a, const float* __restrict__ rel_m,
    float* __restrict__ cw, float* __restrict__ cb) {
  int b  = blockIdx.x;            // ((l*R)+r)*2+kv
  int kv = b & 1;
  int r  = (b >> 1) % R;
  int l  = b / (2 * R);
  int t_src = (r == 0) ? 0 : 1;
  int i_w   = (kv == 0) ? 0 : 2;
  const float* W    = kqv_w + ((size_t)((l*3 + i_w)*2 + t_src)) * D * D;
  const float* bvec = kqv_b + ((size_t)((l*3 + i_w)*2 + t_src)) * D;
  const float* rel  = ((kv == 0) ? rel_a : rel_m) + ((size_t)(l*R + r)) * H * 32 * 32;
  float* Cout = cw + (size_t)b * D * D;
  float* cbo  = cb + (size_t)b * D;
  for (int idx = threadIdx.x; idx < D * D; idx += 256) {
    int i = idx / D, j = idx % D;
    int h = j >> 5, f = j & 31;
    const float* relh = rel + h * 32 * 32;
    float sum = 0.f;
#pragma unroll
    for (int d = 0; d < 32; ++d) sum += W[i*D + (h*32 + d)] * relh[d*32 + f];
    Cout[idx] = sum;
  }
  if (threadIdx.x < D) {
    int j = threadIdx.x;
    int h = j >> 5, f = j & 31;
    const float* relh = rel + h * 32 * 32;
    float sum = 0.f;
#pragma unroll
    for (int d = 0; d < 32; ++d) sum += bvec[h*32 + d] * relh[d*32 + f];
    cbo[j] = sum;
  }
}

// ------------- pack weight matrices into MFMA-fragment order (hi/lo split) -------
__global__ __launch_bounds__(256) void pack_b(
    const float* __restrict__ proj_w, const float* __restrict__ kqv_w,
    const float* __restrict__ out_w, const float* __restrict__ cls_w,
    const float* __restrict__ cw,
    unsigned short* __restrict__ phi, unsigned short* __restrict__ plo) {
  int slot = blockIdx.x;
  const float* src; int ncol = 128;
  if (slot == 0) src = proj_w;
  else if (slot == 1) src = proj_w + D * D;
  else if (slot == 22) { src = cls_w; ncol = 40; }
  else {
    int l = (slot - 2) / 10, k = (slot - 2) % 10;
    if (k == 0)      src = kqv_w + ((size_t)((l*3 + 1)*2 + 0)) * D * D;
    else if (k == 1) src = kqv_w + ((size_t)((l*3 + 1)*2 + 1)) * D * D;
    else if (k < 8)  { int idx = k - 2; src = cw + ((size_t)((l*R)*2 + idx)) * D * D; }
    else             src = out_w + ((size_t)(l*2 + (k - 8))) * D * D;
  }
  int nt = (ncol + 15) / 16;
  int total = nt * 4 * 512;
  unsigned short* ph = phi + (size_t)slot * SLOT_ELEMS;
  unsigned short* pl = plo + (size_t)slot * SLOT_ELEMS;
  for (int idx = threadIdx.x; idx < total; idx += 256) {
    int j = idx & 7, lane = (idx >> 3) & 63, ks = (idx >> 9) & 3, ct = idx >> 11;
    int k = 4 * (lane >> 4) + (j & 3) + 16 * (j >> 2) + 32 * ks;
    int n = ct * 16 + (lane & 15);
    float v = (n < ncol) ? src[(size_t)k * ncol + n] : 0.f;
    unsigned short h = f2bf(v);
    ph[idx] = h;
    pl[idx] = f2bf(v - bf2f(h));
  }
}

// ---------------- CSR build ----------------
__global__ void count3(const int* __restrict__ ei_w, const int* __restrict__ ei_c,
                       const int* __restrict__ ei_r, int* __restrict__ degz) {
  const int* dst = blockIdx.y == 0 ? ei_w + E : blockIdx.y == 1 ? ei_c + E : ei_r + E;
  int* deg = degz + blockIdx.y * NPP;
  for (int e = blockIdx.x * blockDim.x + threadIdx.x; e < E; e += gridDim.x * blockDim.x)
    atomicAdd(&deg[dst[e]], 1);
}
__global__ void fill3(const int* __restrict__ ei_w, const int* __restrict__ ei_c,
                      const int* __restrict__ ei_r,
                      const int* __restrict__ rp_w, const int* __restrict__ rp_c,
                      const int* __restrict__ rp_r,
                      int* __restrict__ cntz, int* __restrict__ colz) {
  int rel = blockIdx.y;
  const int* ei = rel == 0 ? ei_w : rel == 1 ? ei_c : ei_r;
  const int* dst = ei + E;
  const int* rp  = rel == 0 ? rp_w : rel == 1 ? rp_c : rp_r;
  int* cnt = cntz + rel * NPP;
  int* col = colz + rel * E;
  for (int e = blockIdx.x * blockDim.x + threadIdx.x; e < E; e += gridDim.x * blockDim.x) {
    int d = dst[e];
    int pos = atomicAdd(&cnt[d], 1);
    col[rp[d] + pos] = ei[e];          // store SOURCE node directly
  }
}

// 3-phase exclusive scan over three 100000-length deg arrays (contiguous)
__global__ __launch_bounds__(256) void scan_partial(const int* __restrict__ degz,
                                                    int* __restrict__ bsum) {
  int blk = blockIdx.x, rel = blk / 25, t25 = blk % 25;
  const int* deg = degz + rel * NPP + t25 * 4096;
  int nrem = min(4096, NPP - t25 * 4096);
  int base = threadIdx.x * 16;
  int s = 0;
  if (base < nrem) {
#pragma unroll
    for (int i4 = 0; i4 < 4; ++i4) {
      int4 v = *(const int4*)(deg + base + i4 * 4);
      s += v.x + v.y + v.z + v.w;
    }
  }
  __shared__ int sm[256];
  sm[threadIdx.x] = s; __syncthreads();
  for (int o = 128; o > 0; o >>= 1) {
    if (threadIdx.x < o) sm[threadIdx.x] += sm[threadIdx.x + o];
    __syncthreads();
  }
  if (threadIdx.x == 0) bsum[blk] = sm[0];
}
__global__ __launch_bounds__(128) void scan_offsets(const int* __restrict__ bsum,
                                                    int* __restrict__ boff,
                                                    int* rp_w, int* rp_c, int* rp_r) {
  __shared__ int sm[128];
  int t = threadIdx.x;
  sm[t] = (t < 75) ? bsum[t] : 0;
  __syncthreads();
  for (int o = 1; o < 128; o <<= 1) {
    int v = (t >= o) ? sm[t - o] : 0;
    __syncthreads(); sm[t] += v; __syncthreads();
  }
  if (t < 75) {
    int rel = t / 25;
    int base = rel ? sm[rel * 25 - 1] : 0;
    boff[t] = (t % 25 == 0) ? 0 : (sm[t - 1] - base);
    if (t % 25 == 24) {
      int total = sm[t] - base;
      if (rel == 0) rp_w[NPP] = total;
      else if (rel == 1) rp_c[NPP] = total;
      else rp_r[NA] = total;
    }
  }
}
__global__ __launch_bounds__(256) void scan_final(const int* __restrict__ degz,
                                                  const int* __restrict__ boff,
                                                  int* rp_w, int* rp_c, int* rp_r) {
  int blk = blockIdx.x, rel = blk / 25, t25 = blk % 25;
  const int* deg = degz + rel * NPP + t25 * 4096;
  int* rp = (rel == 0 ? rp_w : rel == 1 ? rp_c : rp_r) + t25 * 4096;
  int nrem = min(4096, NPP - t25 * 4096);
  int base = threadIdx.x * 16;
  bool ok = base < nrem;
  int v[16]; int s = 0;
  if (ok) {
#pragma unroll
    for (int i4 = 0; i4 < 4; ++i4) {
      int4 u = *(const int4*)(deg + base + i4 * 4);
      v[i4*4+0] = u.x; v[i4*4+1] = u.y; v[i4*4+2] = u.z; v[i4*4+3] = u.w;
      s += u.x + u.y + u.z + u.w;
    }
  }
  __shared__ int sm[256];
  sm[threadIdx.x] = s; __syncthreads();
  for (int o = 1; o < 256; o <<= 1) {
    int x = (threadIdx.x >= o) ? sm[threadIdx.x - o] : 0;
    __syncthreads(); sm[threadIdx.x] += x; __syncthreads();
  }
  int run = boff[blk] + sm[threadIdx.x] - s;
  if (ok) {
    int w[16];
#pragma unroll
    for (int i = 0; i < 16; ++i) { w[i] = run; run += v[i]; }
#pragma unroll
    for (int i4 = 0; i4 < 4; ++i4) *(int4*)(rp + base + i4 * 4) = *(const int4*)&w[i4*4];
  }
}

// -------- per-destination attention (no-max softmax: scores are O(1)) -----------
// 1 wave / node; lane holds dims {2l, 2l+1}; head = lane>>4; one ushort4 gather
// per edge from the pair-interleaved kv buffer [k0,v0,k1,v1,...]:
//   u.x=k_{2l}, u.y=v_{2l}, u.z=k_{2l+1}, u.w=v_{2l+1}
template<int FIRST, int LAST>
__global__ __launch_bounds__(256, 8) void attn3(
    const int* __restrict__ rp, const int* __restrict__ col,
    const unsigned short* __restrict__ q, const unsigned short* __restrict__ kv,
    const float* __restrict__ prel, int ndst,
    float* __restrict__ z_st, float* __restrict__ acc) {
  int dst  = blockIdx.x * 4 + (threadIdx.x >> 6);
  int lane = threadIdx.x & 63;
  if (dst >= ndst) return;
  int head = lane >> 4;
  const float scale = 0.17677669529663688f; // 1/sqrt(32)
  float pr = prel[head] * scale;
  ushort2 qv = *(const ushort2*)(q + (size_t)dst * D + lane * 2);
  float qx = bf2f(qv.x), qy = bf2f(qv.y);
  float z, ax, ay;
  if (FIRST) { z = 0.f; ax = 0.f; ay = 0.f; }
  else {
    z = z_st[dst * H + head];
    float2 a = *(float2*)(acc + (size_t)dst * D + lane * 2);
    ax = a.x; ay = a.y;
  }
  int e0 = rp[dst], e1 = rp[dst + 1];
  int j = e0;
  for (; j + 1 < e1; j += 2) {
    int s0 = col[j], s1 = col[j + 1];
    ushort4 u = *(const ushort4*)(kv + (size_t)s0 * 256 + lane * 4);
    ushort4 w = *(const ushort4*)(kv + (size_t)s1 * 256 + lane * 4);
    float p0 = qx * bf2f(u.x) + qy * bf2f(u.z);
    float p1 = qx * bf2f(w.x) + qy * bf2f(w.z);
    p0 += __shfl_xor(p0, 1); p1 += __shfl_xor(p1, 1);
    p0 += __shfl_xor(p0, 2); p1 += __shfl_xor(p1, 2);
    p0 += __shfl_xor(p0, 4); p1 += __shfl_xor(p1, 4);
    p0 += __shfl_xor(p0, 8); p1 += __shfl_xor(p1, 8);
    float ea = __expf(p0 * pr);
    float eb = __expf(p1 * pr);
    z  += ea + eb;
    ax += ea * bf2f(u.y) + eb * bf2f(w.y);
    ay += ea * bf2f(u.w) + eb * bf2f(w.w);
  }
  if (j < e1) {
    int s0 = col[j];
    ushort4 u = *(const ushort4*)(kv + (size_t)s0 * 256 + lane * 4);
    float p0 = qx * bf2f(u.x) + qy * bf2f(u.z);
    p0 += __shfl_xor(p0, 1);
    p0 += __shfl_xor(p0, 2);
    p0 += __shfl_xor(p0, 4);
    p0 += __shfl_xor(p0, 8);
    float ea = __expf(p0 * pr);
    z  += ea;
    ax += ea * bf2f(u.y);
    ay += ea * bf2f(u.w);
  }
  if (LAST) {
    float inv = 1.f / (z + 1e-16f);
    *(float2*)(acc + (size_t)dst * D + lane * 2) = make_float2(ax * inv, ay * inv);
  } else {
    *(float2*)(acc + (size_t)dst * D + lane * 2) = make_float2(ax, ay);
    if ((lane & 15) == 0) z_st[dst * H + head] = z;
  }
}

extern "C" void kernel_launch(void* const* d_in, const int* in_sizes, int n_in,
                              void* d_out, int out_size, void* d_ws, size_t ws_size,
                              hipStream_t stream) {
  const float* x_a    = (const float*)d_in[0];
  const float* x_p    = (const float*)d_in[1];
  const int*   ei_w   = (const int*)d_in[2];
  const int*   ei_r   = (const int*)d_in[3];
  const int*   ei_c   = (const int*)d_in[4];
  const float* proj_w = (const float*)d_in[5];
  const float* proj_b = (const float*)d_in[6];
  const float* kqv_w  = (const float*)d_in[7];
  const float* kqv_b  = (const float*)d_in[8];
  const float* out_w  = (const float*)d_in[9];
  const float* out_b  = (const float*)d_in[10];
  const float* rel_a  = (const float*)d_in[11];
  const float* rel_m  = (const float*)d_in[12];
  const float* p_rel  = (const float*)d_in[13];
  const float* skip   = (const float*)d_in[14];
  const float* cls_w  = (const float*)d_in[15];
  const float* cls_b  = (const float*)d_in[16];
  float* out = (float*)d_out;

  const size_t NF = (size_t)NA * D;   // 12.8M
  float* ws    = (float*)d_ws;
  float* h_a   = ws;
  float* h_p   = h_a + NF;
  float* b_acc = h_p + NF;
  unsigned short* b_q  = (unsigned short*)(b_acc + NF);   // NF
  unsigned short* b_kv = b_q + NF;                        // 2*NF pair-interleaved k/v
  float* cw    = (float*)(b_kv + 2 * NF);       // 12*D*D
  float* cb    = cw + 12 * D * D;               // 12*D
  float* z_st  = cb + 12 * D;                   // NPP*H
  unsigned short* phi = (unsigned short*)(z_st + (size_t)NPP * H);  // 23*SLOT_ELEMS
  unsigned short* plo = phi + (size_t)NSLOT * SLOT_ELEMS;
  int* ip    = (int*)(plo + (size_t)NSLOT * SLOT_ELEMS);
  int* rp_w  = ip;                      // NPP+1
  int* rp_c  = rp_w + (NPP + 1);
  int* rp_r  = rp_c + (NPP + 1);
  int* degz  = rp_r + (NA + 1);         // 3*NPP deg + 3*NPP cnt (contiguous)
  int* cntz  = degz + 3 * NPP;
  int* colz  = cntz + 3 * NPP;          // 3*E (src-node per CSR entry)
  int* bsum  = colz + 3 * E;            // 75
  int* boff  = bsum + 128;              // 75
  size_t need_bytes = (size_t)((char*)(boff + 128) - (char*)d_ws);
  if (ws_size < need_bytes) return;

  hipMemsetAsync(degz, 0, sizeof(int) * 6 * (size_t)NPP, stream);

  count3<<<dim3(256, 3), 256, 0, stream>>>(ei_w, ei_c, ei_r, degz);
  scan_partial<<<75, 256, 0, stream>>>(degz, bsum);
  scan_offsets<<<1, 128, 0, stream>>>(bsum, boff, rp_w, rp_c, rp_r);
  scan_final<<<75, 256, 0, stream>>>(degz, boff, rp_w, rp_c, rp_r);
  fill3<<<dim3(256, 3), 256, 0, stream>>>(ei_w, ei_c, ei_r, rp_w, rp_c, rp_r, cntz, colz);
  int* col_w = colz;
  int* col_c = colz + E;
  int* col_r = colz + 2 * E;

  combine_w<<<12, 256, 0, stream>>>(kqv_w, kqv_b, rel_a, rel_m, cw, cb);
  pack_b<<<NSLOT, 256, 0, stream>>>(proj_w, kqv_w, out_w, cls_w, cw, phi, plo);

  auto PH = [&](int s){ return phi + (size_t)s * SLOT_ELEMS; };
  auto PL = [&](int s){ return plo + (size_t)s * SLOT_ELEMS; };

  const int GB = (NA + 63) / 64;       // 1563
  const dim3 G1(GB, 1), GKV(GB, 2);
  // initial projections (fp32 out)
  gemm3<8, 128, 0, false, false><<<G1, 256, 0, stream>>>(
      x_a, PH(0), PL(0), proj_b,     h_a, nullptr, NA);
  gemm3<8, 128, 0, false, false><<<G1, 256, 0, stream>>>(
      x_p, PH(1), PL(1), proj_b + D, h_p, nullptr, NPP);

  for (int l = 0; l < L; ++l) {
    const int SQA = 2 + l * 10 + 0, SQP = 2 + l * 10 + 1;
    auto SKV = [&](int r){ return 2 + l * 10 + 2 + r * 2; };  // k slot; v slot = +1 (adjacent)
    const int SO0 = 2 + l * 10 + 8, SO1 = 2 + l * 10 + 9;
    const float* bq_a = kqv_b + ((size_t)((l*3 + 1)*2 + 0)) * D;
    const float* bq_p = kqv_b + ((size_t)((l*3 + 1)*2 + 1)) * D;
    auto CB2 = [&](int r){ return cb + ((size_t)((l*R + r)*2)) * D; };  // 256 floats (k|v)

    // ---- author destination (rev_writes r=1, src=paper) ----
    gemm3<8, 128, 1, false, false><<<G1, 256, 0, stream>>>(
        h_a, PH(SQA), PL(SQA), bq_a, b_q, nullptr, NA);
    gemm_kv<<<GKV, 256, 0, stream>>>(
        h_p, PH(SKV(1)), PL(SKV(1)), CB2(1), b_kv, NPP);
    attn3<1, 1><<<(NA + 3) / 4, 256, 0, stream>>>(
        rp_r, col_r, b_q, b_kv, p_rel + (size_t)(l*R + 1) * H, NA, z_st, b_acc);
    // writes-relation K/V from OLD h_a (before author update)
    gemm_kv<<<GKV, 256, 0, stream>>>(
        h_a, PH(SKV(0)), PL(SKV(0)), CB2(0), b_kv, NA);
    // author out-mix (in-place h_a)
    gemm3<8, 128, 0, true, true><<<G1, 256, 0, stream>>>(
        b_acc, PH(SO0), PL(SO0), out_b + (size_t)(l*2 + 0) * D, h_a,
        skip + l*2 + 0, NA);

    // ---- paper destination: joint softmax over writes(r=0) + cites(r=2) ----
    gemm3<8, 128, 1, false, false><<<G1, 256, 0, stream>>>(
        h_p, PH(SQP), PL(SQP), bq_p, b_q, nullptr, NPP);
    attn3<1, 0><<<(NPP + 3) / 4, 256, 0, stream>>>(
        rp_w, col_w, b_q, b_kv, p_rel + (size_t)(l*R + 0) * H, NPP, z_st, b_acc);
    gemm_kv<<<GKV, 256, 0, stream>>>(
        h_p, PH(SKV(2)), PL(SKV(2)), CB2(2), b_kv, NPP);
    attn3<0, 1><<<(NPP + 3) / 4, 256, 0, stream>>>(
        rp_c, col_c, b_q, b_kv, p_rel + (size_t)(l*R + 2) * H, NPP, z_st, b_acc);
    gemm3<8, 128, 0, true, true><<<G1, 256, 0, stream>>>(
        b_acc, PH(SO1), PL(SO1), out_b + (size_t)(l*2 + 1) * D, h_p,
        skip + l*2 + 1, NPP);
  }

  gemm3<3, 40, 0, false, false><<<G1, 256, 0, stream>>>(
      h_p, PH(22), PL(22), cls_b, out, nullptr, NPP);
}

// Round 7
// 1187.722 us; speedup vs baseline: 1.1761x; 1.1511x over previous
//
#include <hip/hip_runtime.h>
#include <hip/hip_bf16.h>
#include <math.h>

constexpr int NA  = 100000;
constexpr int NPP = 100000;
constexpr int D   = 128;
constexpr int H   = 4;
constexpr int E   = 400000;
constexpr int R   = 3;
constexpr int L   = 2;
constexpr int NSLOT = 23;
constexpr int SLOT_ELEMS = 8 * 4 * 512;   // 8 col-tiles * 4 ksteps * 512 bf16

using s8v = __attribute__((ext_vector_type(8))) short;
using f4v = __attribute__((ext_vector_type(4))) float;
typedef unsigned short ushort_t;

static __device__ __forceinline__ unsigned short f2bf(float f) {
  unsigned u = __float_as_uint(f);
  return (unsigned short)((u + 0x7fffu + ((u >> 16) & 1u)) >> 16);
}
static __device__ __forceinline__ float bf2f(unsigned short s) {
  return __uint_as_float(((unsigned)s) << 16);
}
static __device__ __forceinline__ float gelu_f(float x) {
  return 0.5f * x * (1.0f + erff(x * 0.70710678118654752f));
}
static __device__ __forceinline__ float elu_f(float x) {
  return x > 0.0f ? x : expm1f(x);
}

// =============== MFMA GEMM: C = act(A[M,128]) @ B + bias ========================
// block = 256 thr = 4 waves; wave computes 16 rows x NT16*16 cols. acc = 4*NT16.
// A fragment: lane l -> row = l&15, k(i) = 4*(l>>4) + (i&3) + 16*(i>>2) + 32*ks.
// B packed by pack_b in the SAME k-order -> any hw k-permutation cancels.
// C/D layout (m89-verified): col = lane&15, row = (lane>>4)*4 + reg.
// TA=float: A split hi/lo, 3 MFMAs/tile (near-fp32). TA=ushort: A is bf16,
// 2 MFMAs/tile (ahi*bhi + ahi*blo; B precision kept).
// STORE: 0 = fp32 out, 1 = bf16 out. MIX: bf16 h residual read-modify-write.
template<int NT16, int NCOLS, int STORE, bool GELU_A, bool MIX, typename TA>
__global__ __launch_bounds__(256, 4) void gemm3(
    const TA* __restrict__ A,
    const ushort_t* __restrict__ Bhi, const ushort_t* __restrict__ Blo,
    const float* __restrict__ bias, void* __restrict__ Cv,
    const float* __restrict__ skip_ptr, int M) {
  const int lane = threadIdx.x & 63;
  const int wave = threadIdx.x >> 6;
  const int row0 = blockIdx.x * 64 + wave * 16;
  const int g = lane >> 4, li = lane & 15;
  constexpr bool AFP32 = sizeof(TA) == 4;

  f4v acc[NT16];
#pragma unroll
  for (int ct = 0; ct < NT16; ++ct) acc[ct] = f4v{0.f, 0.f, 0.f, 0.f};

  int arow = row0 + li;
  if (arow >= M) arow = M - 1;             // clamp (stores guarded)

#pragma unroll
  for (int ks = 0; ks < 4; ++ks) {
    s8v ahi, alo;
    if constexpr (AFP32) {
      const float* ap = (const float*)A + (size_t)arow * 128 + ks * 32 + g * 4;
      float4 u0 = *(const float4*)ap;
      float4 u1 = *(const float4*)(ap + 16);
      float x[8] = {u0.x, u0.y, u0.z, u0.w, u1.x, u1.y, u1.z, u1.w};
#pragma unroll
      for (int i = 0; i < 8; ++i) {
        float v = GELU_A ? gelu_f(x[i]) : x[i];
        unsigned short h = f2bf(v);
        ahi[i] = (short)h;
        alo[i] = (short)f2bf(v - bf2f(h));
      }
    } else {
      const ushort_t* ap = (const ushort_t*)A + (size_t)arow * 128 + ks * 32 + g * 4;
      ushort4 u0 = *(const ushort4*)ap;
      ushort4 u1 = *(const ushort4*)(ap + 16);
      ushort_t uu[8] = {u0.x, u0.y, u0.z, u0.w, u1.x, u1.y, u1.z, u1.w};
#pragma unroll
      for (int i = 0; i < 8; ++i) {
        if (GELU_A) ahi[i] = (short)f2bf(gelu_f(bf2f(uu[i])));
        else        ahi[i] = (short)uu[i];
      }
    }
#pragma unroll
    for (int ct = 0; ct < NT16; ++ct) {
      size_t boff = (size_t)((ct * 4 + ks) << 9) + (lane << 3);
      s8v bhi = *(const s8v*)(Bhi + boff);
      s8v blo = *(const s8v*)(Blo + boff);
      acc[ct] = __builtin_amdgcn_mfma_f32_16x16x32_bf16(ahi, bhi, acc[ct], 0, 0, 0);
      if constexpr (AFP32)
        acc[ct] = __builtin_amdgcn_mfma_f32_16x16x32_bf16(alo, bhi, acc[ct], 0, 0, 0);
      acc[ct] = __builtin_amdgcn_mfma_f32_16x16x32_bf16(ahi, blo, acc[ct], 0, 0, 0);
    }
  }

  float sskip = 0.f;
  if (MIX) sskip = 1.f / (1.f + __expf(-*skip_ptr));
#pragma unroll
  for (int ct = 0; ct < NT16; ++ct) {
    int col = ct * 16 + li;
    bool colok = (col < NCOLS);
    float bv = colok ? bias[col] : 0.f;
#pragma unroll
    for (int r = 0; r < 4; ++r) {
      int grow = row0 + g * 4 + r;
      if (grow < M && colok) {
        float v = acc[ct][r] + bv;
        size_t off = (size_t)grow * NCOLS + col;
        if constexpr (MIX) {            // bf16 h residual
          ushort_t* Cp = (ushort_t*)Cv;
          float hprev = bf2f(Cp[off]);
          Cp[off] = f2bf(elu_f(sskip * v + (1.f - sskip) * hprev));
        } else if constexpr (STORE == 1) {
          ((ushort_t*)Cv)[off] = f2bf(v);
        } else {
          ((float*)Cv)[off] = v;
        }
      }
    }
  }
}

// ============ KV GEMM: column-half split, pair-interleaved coalesced store ======
// A is bf16 h. grid (GB, 2); blockIdx.y = column half; 4 K-tiles + 4 V-tiles.
// 2 MFMAs per tile (bf16 A). Store ushort2{k_c, v_c} at kv[row*256 + 2c].
__global__ __launch_bounds__(256, 4) void gemm_kv(
    const ushort_t* __restrict__ A,
    const ushort_t* __restrict__ Bhi, const ushort_t* __restrict__ Blo,
    const float* __restrict__ bias, ushort_t* __restrict__ kvout, int M) {
  const int lane = threadIdx.x & 63;
  const int wave = threadIdx.x >> 6;
  const int row0 = blockIdx.x * 64 + wave * 16;
  const int g = lane >> 4, li = lane & 15;
  const int ch = blockIdx.y;

  f4v acc[8];
#pragma unroll
  for (int t = 0; t < 8; ++t) acc[t] = f4v{0.f, 0.f, 0.f, 0.f};

  int arow = row0 + li;
  if (arow >= M) arow = M - 1;
  const ushort_t* ap = A + (size_t)arow * 128 + g * 4;

#pragma unroll
  for (int ks = 0; ks < 4; ++ks) {
    ushort4 u0 = *(const ushort4*)(ap + ks * 32);
    ushort4 u1 = *(const ushort4*)(ap + ks * 32 + 16);
    s8v ahi;
    ahi[0] = (short)u0.x; ahi[1] = (short)u0.y; ahi[2] = (short)u0.z; ahi[3] = (short)u0.w;
    ahi[4] = (short)u1.x; ahi[5] = (short)u1.y; ahi[6] = (short)u1.z; ahi[7] = (short)u1.w;
#pragma unroll
    for (int t = 0; t < 4; ++t) {
      int ct = ch * 4 + t;
      size_t bk = (size_t)((ct * 4 + ks) << 9) + (lane << 3);
      s8v kh = *(const s8v*)(Bhi + bk);
      s8v kl = *(const s8v*)(Blo + bk);
      acc[t] = __builtin_amdgcn_mfma_f32_16x16x32_bf16(ahi, kh, acc[t], 0, 0, 0);
      acc[t] = __builtin_amdgcn_mfma_f32_16x16x32_bf16(ahi, kl, acc[t], 0, 0, 0);
      size_t bv = (size_t)SLOT_ELEMS + bk;        // V slot adjacent
      s8v vh = *(const s8v*)(Bhi + bv);
      s8v vl = *(const s8v*)(Blo + bv);
      acc[4 + t] = __builtin_amdgcn_mfma_f32_16x16x32_bf16(ahi, vh, acc[4 + t], 0, 0, 0);
      acc[4 + t] = __builtin_amdgcn_mfma_f32_16x16x32_bf16(ahi, vl, acc[4 + t], 0, 0, 0);
    }
  }

#pragma unroll
  for (int t = 0; t < 4; ++t) {
    int col = ch * 64 + t * 16 + li;
    float bk = bias[col], bv = bias[128 + col];
#pragma unroll
    for (int r = 0; r < 4; ++r) {
      int grow = row0 + g * 4 + r;
      if (grow < M) {
        ushort2 o;
        o.x = f2bf(acc[t][r] + bk);
        o.y = f2bf(acc[4 + t][r] + bv);
        *(ushort2*)(kvout + (size_t)grow * 256 + 2 * col) = o;
      }
    }
  }
}

// ------------- combined weights: cw = W @ blockdiag(rel), cb = b @ blockdiag(rel)
__global__ __launch_bounds__(256) void combine_w(
    const float* __restrict__ kqv_w, const float* __restrict__ kqv_b,
    const float* __restrict__ rel_a, const float* __restrict__ rel_m,
    float* __restrict__ cw, float* __restrict__ cb) {
  int b  = blockIdx.x;            // ((l*R)+r)*2+kv
  int kv = b & 1;
  int r  = (b >> 1) % R;
  int l  = b / (2 * R);
  int t_src = (r == 0) ? 0 : 1;
  int i_w   = (kv == 0) ? 0 : 2;
  const float* W    = kqv_w + ((size_t)((l*3 + i_w)*2 + t_src)) * D * D;
  const float* bvec = kqv_b + ((size_t)((l*3 + i_w)*2 + t_src)) * D;
  const float* rel  = ((kv == 0) ? rel_a : rel_m) + ((size_t)(l*R + r)) * H * 32 * 32;
  float* Cout = cw + (size_t)b * D * D;
  float* cbo  = cb + (size_t)b * D;
  for (int idx = threadIdx.x; idx < D * D; idx += 256) {
    int i = idx / D, j = idx % D;
    int h = j >> 5, f = j & 31;
    const float* relh = rel + h * 32 * 32;
    float sum = 0.f;
#pragma unroll
    for (int d = 0; d < 32; ++d) sum += W[i*D + (h*32 + d)] * relh[d*32 + f];
    Cout[idx] = sum;
  }
  if (threadIdx.x < D) {
    int j = threadIdx.x;
    int h = j >> 5, f = j & 31;
    const float* relh = rel + h * 32 * 32;
    float sum = 0.f;
#pragma unroll
    for (int d = 0; d < 32; ++d) sum += bvec[h*32 + d] * relh[d*32 + f];
    cbo[j] = sum;
  }
}

// ------------- pack weight matrices into MFMA-fragment order (hi/lo split) -------
__global__ __launch_bounds__(256) void pack_b(
    const float* __restrict__ proj_w, const float* __restrict__ kqv_w,
    const float* __restrict__ out_w, const float* __restrict__ cls_w,
    const float* __restrict__ cw,
    ushort_t* __restrict__ phi, ushort_t* __restrict__ plo) {
  int slot = blockIdx.x;
  const float* src; int ncol = 128;
  if (slot == 0) src = proj_w;
  else if (slot == 1) src = proj_w + D * D;
  else if (slot == 22) { src = cls_w; ncol = 40; }
  else {
    int l = (slot - 2) / 10, k = (slot - 2) % 10;
    if (k == 0)      src = kqv_w + ((size_t)((l*3 + 1)*2 + 0)) * D * D;
    else if (k == 1) src = kqv_w + ((size_t)((l*3 + 1)*2 + 1)) * D * D;
    else if (k < 8)  { int idx = k - 2; src = cw + ((size_t)((l*R)*2 + idx)) * D * D; }
    else             src = out_w + ((size_t)(l*2 + (k - 8))) * D * D;
  }
  int nt = (ncol + 15) / 16;
  int total = nt * 4 * 512;
  ushort_t* ph = phi + (size_t)slot * SLOT_ELEMS;
  ushort_t* pl = plo + (size_t)slot * SLOT_ELEMS;
  for (int idx = threadIdx.x; idx < total; idx += 256) {
    int j = idx & 7, lane = (idx >> 3) & 63, ks = (idx >> 9) & 3, ct = idx >> 11;
    int k = 4 * (lane >> 4) + (j & 3) + 16 * (j >> 2) + 32 * ks;
    int n = ct * 16 + (lane & 15);
    float v = (n < ncol) ? src[(size_t)k * ncol + n] : 0.f;
    unsigned short h = f2bf(v);
    ph[idx] = h;
    pl[idx] = f2bf(v - bf2f(h));
  }
}

// ---------------- CSR build ----------------
__global__ void count3(const int* __restrict__ ei_w, const int* __restrict__ ei_c,
                       const int* __restrict__ ei_r, int* __restrict__ degz) {
  const int* dst = blockIdx.y == 0 ? ei_w + E : blockIdx.y == 1 ? ei_c + E : ei_r + E;
  int* deg = degz + blockIdx.y * NPP;
  for (int e = blockIdx.x * blockDim.x + threadIdx.x; e < E; e += gridDim.x * blockDim.x)
    atomicAdd(&deg[dst[e]], 1);
}
__global__ void fill3(const int* __restrict__ ei_w, const int* __restrict__ ei_c,
                      const int* __restrict__ ei_r,
                      const int* __restrict__ rp_w, const int* __restrict__ rp_c,
                      const int* __restrict__ rp_r,
                      int* __restrict__ cntz, int* __restrict__ colz) {
  int rel = blockIdx.y;
  const int* ei = rel == 0 ? ei_w : rel == 1 ? ei_c : ei_r;
  const int* dst = ei + E;
  const int* rp  = rel == 0 ? rp_w : rel == 1 ? rp_c : rp_r;
  int* cnt = cntz + rel * NPP;
  int* col = colz + rel * E;
  for (int e = blockIdx.x * blockDim.x + threadIdx.x; e < E; e += gridDim.x * blockDim.x) {
    int d = dst[e];
    int pos = atomicAdd(&cnt[d], 1);
    col[rp[d] + pos] = ei[e];          // store SOURCE node directly
  }
}

// 3-phase exclusive scan over three 100000-length deg arrays (contiguous)
__global__ __launch_bounds__(256) void scan_partial(const int* __restrict__ degz,
                                                    int* __restrict__ bsum) {
  int blk = blockIdx.x, rel = blk / 25, t25 = blk % 25;
  const int* deg = degz + rel * NPP + t25 * 4096;
  int nrem = min(4096, NPP - t25 * 4096);
  int base = threadIdx.x * 16;
  int s = 0;
  if (base < nrem) {
#pragma unroll
    for (int i4 = 0; i4 < 4; ++i4) {
      int4 v = *(const int4*)(deg + base + i4 * 4);
      s += v.x + v.y + v.z + v.w;
    }
  }
  __shared__ int sm[256];
  sm[threadIdx.x] = s; __syncthreads();
  for (int o = 128; o > 0; o >>= 1) {
    if (threadIdx.x < o) sm[threadIdx.x] += sm[threadIdx.x + o];
    __syncthreads();
  }
  if (threadIdx.x == 0) bsum[blk] = sm[0];
}
__global__ __launch_bounds__(128) void scan_offsets(const int* __restrict__ bsum,
                                                    int* __restrict__ boff,
                                                    int* rp_w, int* rp_c, int* rp_r) {
  __shared__ int sm[128];
  int t = threadIdx.x;
  sm[t] = (t < 75) ? bsum[t] : 0;
  __syncthreads();
  for (int o = 1; o < 128; o <<= 1) {
    int v = (t >= o) ? sm[t - o] : 0;
    __syncthreads(); sm[t] += v; __syncthreads();
  }
  if (t < 75) {
    int rel = t / 25;
    int base = rel ? sm[rel * 25 - 1] : 0;
    boff[t] = (t % 25 == 0) ? 0 : (sm[t - 1] - base);
    if (t % 25 == 24) {
      int total = sm[t] - base;
      if (rel == 0) rp_w[NPP] = total;
      else if (rel == 1) rp_c[NPP] = total;
      else rp_r[NA] = total;
    }
  }
}
__global__ __launch_bounds__(256) void scan_final(const int* __restrict__ degz,
                                                  const int* __restrict__ boff,
                                                  int* rp_w, int* rp_c, int* rp_r) {
  int blk = blockIdx.x, rel = blk / 25, t25 = blk % 25;
  const int* deg = degz + rel * NPP + t25 * 4096;
  int* rp = (rel == 0 ? rp_w : rel == 1 ? rp_c : rp_r) + t25 * 4096;
  int nrem = min(4096, NPP - t25 * 4096);
  int base = threadIdx.x * 16;
  bool ok = base < nrem;
  int v[16]; int s = 0;
  if (ok) {
#pragma unroll
    for (int i4 = 0; i4 < 4; ++i4) {
      int4 u = *(const int4*)(deg + base + i4 * 4);
      v[i4*4+0] = u.x; v[i4*4+1] = u.y; v[i4*4+2] = u.z; v[i4*4+3] = u.w;
      s += u.x + u.y + u.z + u.w;
    }
  }
  __shared__ int sm[256];
  sm[threadIdx.x] = s; __syncthreads();
  for (int o = 1; o < 256; o <<= 1) {
    int x = (threadIdx.x >= o) ? sm[threadIdx.x - o] : 0;
    __syncthreads(); sm[threadIdx.x] += x; __syncthreads();
  }
  int run = boff[blk] + sm[threadIdx.x] - s;
  if (ok) {
    int w[16];
#pragma unroll
    for (int i = 0; i < 16; ++i) { w[i] = run; run += v[i]; }
#pragma unroll
    for (int i4 = 0; i4 < 4; ++i4) *(int4*)(rp + base + i4 * 4) = *(const int4*)&w[i4*4];
  }
}

// -------- per-destination attention (no-max softmax: scores are O(1)) -----------
// 1 wave / node; lane holds dims {2l, 2l+1}; head = lane>>4; one ushort4 gather
// per edge from the pair-interleaved kv buffer [k0,v0,k1,v1,...]:
//   u.x=k_{2l}, u.y=v_{2l}, u.z=k_{2l+1}, u.w=v_{2l+1}
// LAST pass writes normalized bf16 aggregate into accb (the q buffer: each wave
// reads its own q row before overwriting it; rows disjoint across waves).
template<int FIRST, int LAST>
__global__ __launch_bounds__(256, 8) void attn3(
    const int* __restrict__ rp, const int* __restrict__ col,
    const ushort_t* __restrict__ q, const ushort_t* __restrict__ kv,
    const float* __restrict__ prel, int ndst,
    float* __restrict__ z_st, float* __restrict__ acc, ushort_t* __restrict__ accb) {
  int dst  = blockIdx.x * 4 + (threadIdx.x >> 6);
  int lane = threadIdx.x & 63;
  if (dst >= ndst) return;
  int head = lane >> 4;
  const float scale = 0.17677669529663688f; // 1/sqrt(32)
  float pr = prel[head] * scale;
  ushort2 qv = *(const ushort2*)(q + (size_t)dst * D + lane * 2);
  float qx = bf2f(qv.x), qy = bf2f(qv.y);
  float z, ax, ay;
  if (FIRST) { z = 0.f; ax = 0.f; ay = 0.f; }
  else {
    z = z_st[dst * H + head];
    float2 a = *(float2*)(acc + (size_t)dst * D + lane * 2);
    ax = a.x; ay = a.y;
  }
  int e0 = rp[dst], e1 = rp[dst + 1];
  int j = e0;
  for (; j + 1 < e1; j += 2) {
    int s0 = col[j], s1 = col[j + 1];
    ushort4 u = *(const ushort4*)(kv + (size_t)s0 * 256 + lane * 4);
    ushort4 w = *(const ushort4*)(kv + (size_t)s1 * 256 + lane * 4);
    float p0 = qx * bf2f(u.x) + qy * bf2f(u.z);
    float p1 = qx * bf2f(w.x) + qy * bf2f(w.z);
    p0 += __shfl_xor(p0, 1); p1 += __shfl_xor(p1, 1);
    p0 += __shfl_xor(p0, 2); p1 += __shfl_xor(p1, 2);
    p0 += __shfl_xor(p0, 4); p1 += __shfl_xor(p1, 4);
    p0 += __shfl_xor(p0, 8); p1 += __shfl_xor(p1, 8);
    float ea = __expf(p0 * pr);
    float eb = __expf(p1 * pr);
    z  += ea + eb;
    ax += ea * bf2f(u.y) + eb * bf2f(w.y);
    ay += ea * bf2f(u.w) + eb * bf2f(w.w);
  }
  if (j < e1) {
    int s0 = col[j];
    ushort4 u = *(const ushort4*)(kv + (size_t)s0 * 256 + lane * 4);
    float p0 = qx * bf2f(u.x) + qy * bf2f(u.z);
    p0 += __shfl_xor(p0, 1);
    p0 += __shfl_xor(p0, 2);
    p0 += __shfl_xor(p0, 4);
    p0 += __shfl_xor(p0, 8);
    float ea = __expf(p0 * pr);
    z  += ea;
    ax += ea * bf2f(u.y);
    ay += ea * bf2f(u.w);
  }
  if (LAST) {
    float inv = 1.f / (z + 1e-16f);
    ushort2 o;
    o.x = f2bf(ax * inv);
    o.y = f2bf(ay * inv);
    *(ushort2*)(accb + (size_t)dst * D + lane * 2) = o;
  } else {
    *(float2*)(acc + (size_t)dst * D + lane * 2) = make_float2(ax, ay);
    if ((lane & 15) == 0) z_st[dst * H + head] = z;
  }
}

extern "C" void kernel_launch(void* const* d_in, const int* in_sizes, int n_in,
                              void* d_out, int out_size, void* d_ws, size_t ws_size,
                              hipStream_t stream) {
  const float* x_a    = (const float*)d_in[0];
  const float* x_p    = (const float*)d_in[1];
  const int*   ei_w   = (const int*)d_in[2];
  const int*   ei_r   = (const int*)d_in[3];
  const int*   ei_c   = (const int*)d_in[4];
  const float* proj_w = (const float*)d_in[5];
  const float* proj_b = (const float*)d_in[6];
  const float* kqv_w  = (const float*)d_in[7];
  const float* kqv_b  = (const float*)d_in[8];
  const float* out_w  = (const float*)d_in[9];
  const float* out_b  = (const float*)d_in[10];
  const float* rel_a  = (const float*)d_in[11];
  const float* rel_m  = (const float*)d_in[12];
  const float* p_rel  = (const float*)d_in[13];
  const float* skip   = (const float*)d_in[14];
  const float* cls_w  = (const float*)d_in[15];
  const float* cls_b  = (const float*)d_in[16];
  float* out = (float*)d_out;

  const size_t NF = (size_t)NA * D;   // 12.8M
  float* ws    = (float*)d_ws;
  // fp32 region first
  float* b_acc = ws;                             // NF (paper attn state)
  float* cw    = b_acc + NF;                     // 12*D*D
  float* cb    = cw + 12 * D * D;                // 12*D
  float* z_st  = cb + 12 * D;                    // NPP*H
  // bf16 region
  ushort_t* h_a  = (ushort_t*)(z_st + (size_t)NPP * H);  // NF
  ushort_t* h_p  = h_a + NF;                             // NF
  ushort_t* b_q  = h_p + NF;                             // NF (q, then bf16 agg)
  ushort_t* b_kv = b_q + NF;                             // 2*NF pair-interleaved
  ushort_t* phi  = b_kv + 2 * NF;                        // 23*SLOT_ELEMS
  ushort_t* plo  = phi + (size_t)NSLOT * SLOT_ELEMS;
  // int region
  int* ip    = (int*)(plo + (size_t)NSLOT * SLOT_ELEMS);
  int* rp_w  = ip;                      // NPP+1
  int* rp_c  = rp_w + (NPP + 1);
  int* rp_r  = rp_c + (NPP + 1);
  int* degz  = rp_r + (NA + 1);         // 3*NPP deg + 3*NPP cnt (contiguous)
  int* cntz  = degz + 3 * NPP;
  int* colz  = cntz + 3 * NPP;          // 3*E (src-node per CSR entry)
  int* bsum  = colz + 3 * E;            // 75
  int* boff  = bsum + 128;              // 75
  size_t need_bytes = (size_t)((char*)(boff + 128) - (char*)d_ws);
  if (ws_size < need_bytes) return;

  hipMemsetAsync(degz, 0, sizeof(int) * 6 * (size_t)NPP, stream);

  count3<<<dim3(256, 3), 256, 0, stream>>>(ei_w, ei_c, ei_r, degz);
  scan_partial<<<75, 256, 0, stream>>>(degz, bsum);
  scan_offsets<<<1, 128, 0, stream>>>(bsum, boff, rp_w, rp_c, rp_r);
  scan_final<<<75, 256, 0, stream>>>(degz, boff, rp_w, rp_c, rp_r);
  fill3<<<dim3(256, 3), 256, 0, stream>>>(ei_w, ei_c, ei_r, rp_w, rp_c, rp_r, cntz, colz);
  int* col_w = colz;
  int* col_c = colz + E;
  int* col_r = colz + 2 * E;

  combine_w<<<12, 256, 0, stream>>>(kqv_w, kqv_b, rel_a, rel_m, cw, cb);
  pack_b<<<NSLOT, 256, 0, stream>>>(proj_w, kqv_w, out_w, cls_w, cw, phi, plo);

  auto PH = [&](int s){ return phi + (size_t)s * SLOT_ELEMS; };
  auto PL = [&](int s){ return plo + (size_t)s * SLOT_ELEMS; };

  const int GB = (NA + 63) / 64;       // 1563
  const dim3 G1(GB, 1), GKV(GB, 2);
  // initial projections (fp32 input, bf16 h out, A split for precision)
  gemm3<8, 128, 1, false, false, float><<<G1, 256, 0, stream>>>(
      x_a, PH(0), PL(0), proj_b,     h_a, nullptr, NA);
  gemm3<8, 128, 1, false, false, float><<<G1, 256, 0, stream>>>(
      x_p, PH(1), PL(1), proj_b + D, h_p, nullptr, NPP);

  for (int l = 0; l < L; ++l) {
    const int SQA = 2 + l * 10 + 0, SQP = 2 + l * 10 + 1;
    auto SKV = [&](int r){ return 2 + l * 10 + 2 + r * 2; };  // k slot; v slot = +1
    const int SO0 = 2 + l * 10 + 8, SO1 = 2 + l * 10 + 9;
    const float* bq_a = kqv_b + ((size_t)((l*3 + 1)*2 + 0)) * D;
    const float* bq_p = kqv_b + ((size_t)((l*3 + 1)*2 + 1)) * D;
    auto CB2 = [&](int r){ return cb + ((size_t)((l*R + r)*2)) * D; };  // 256 floats (k|v)

    // ---- author destination (rev_writes r=1, src=paper) ----
    gemm3<8, 128, 1, false, false, ushort_t><<<G1, 256, 0, stream>>>(
        h_a, PH(SQA), PL(SQA), bq_a, b_q, nullptr, NA);
    gemm_kv<<<GKV, 256, 0, stream>>>(
        h_p, PH(SKV(1)), PL(SKV(1)), CB2(1), b_kv, NPP);
    attn3<1, 1><<<(NA + 3) / 4, 256, 0, stream>>>(
        rp_r, col_r, b_q, b_kv, p_rel + (size_t)(l*R + 1) * H, NA, z_st, b_acc, b_q);
    // writes-relation K/V from OLD h_a (before author update)
    gemm_kv<<<GKV, 256, 0, stream>>>(
        h_a, PH(SKV(0)), PL(SKV(0)), CB2(0), b_kv, NA);
    // author out-mix (in-place bf16 h_a); A = bf16 agg in b_q, gelu applied
    gemm3<8, 128, 1, true, true, ushort_t><<<G1, 256, 0, stream>>>(
        b_q, PH(SO0), PL(SO0), out_b + (size_t)(l*2 + 0) * D, h_a,
        skip + l*2 + 0, NA);

    // ---- paper destination: joint softmax over writes(r=0) + cites(r=2) ----
    gemm3<8, 128, 1, false, false, ushort_t><<<G1, 256, 0, stream>>>(
        h_p, PH(SQP), PL(SQP), bq_p, b_q, nullptr, NPP);
    attn3<1, 0><<<(NPP + 3) / 4, 256, 0, stream>>>(
        rp_w, col_w, b_q, b_kv, p_rel + (size_t)(l*R + 0) * H, NPP, z_st, b_acc, b_q);
    gemm_kv<<<GKV, 256, 0, stream>>>(
        h_p, PH(SKV(2)), PL(SKV(2)), CB2(2), b_kv, NPP);
    attn3<0, 1><<<(NPP + 3) / 4, 256, 0, stream>>>(
        rp_c, col_c, b_q, b_kv, p_rel + (size_t)(l*R + 2) * H, NPP, z_st, b_acc, b_q);
    gemm3<8, 128, 1, true, true, ushort_t><<<G1, 256, 0, stream>>>(
        b_q, PH(SO1), PL(SO1), out_b + (size_t)(l*2 + 1) * D, h_p,
        skip + l*2 + 1, NPP);
  }

  gemm3<3, 40, 0, false, false, ushort_t><<<G1, 256, 0, stream>>>(
      h_p, PH(22), PL(22), cls_b, out, nullptr, NPP);
}

// Round 8
// 992.525 us; speedup vs baseline: 1.4074x; 1.1967x over previous
//
#include <hip/hip_runtime.h>
#include <hip/hip_bf16.h>
#include <math.h>

constexpr int NA  = 100000;
constexpr int NPP = 100000;
constexpr int D   = 128;
constexpr int H   = 4;
constexpr int E   = 400000;
constexpr int R   = 3;
constexpr int L   = 2;
constexpr int NSLOT = 23;
constexpr int SLOT_ELEMS = 8 * 4 * 512;   // 8 col-tiles * 4 ksteps * 512 bf16

using s8v = __attribute__((ext_vector_type(8))) short;
using f4v = __attribute__((ext_vector_type(4))) float;
typedef unsigned short ushort_t;

static __device__ __forceinline__ unsigned short f2bf(float f) {
  unsigned u = __float_as_uint(f);
  return (unsigned short)((u + 0x7fffu + ((u >> 16) & 1u)) >> 16);
}
static __device__ __forceinline__ float bf2f(unsigned short s) {
  return __uint_as_float(((unsigned)s) << 16);
}
static __device__ __forceinline__ float gelu_f(float x) {
  return 0.5f * x * (1.0f + erff(x * 0.70710678118654752f));
}
static __device__ __forceinline__ float elu_f(float x) {
  return x > 0.0f ? x : expm1f(x);
}

// =============== LDS-staged MFMA GEMM: C = act(A[M,128]) @ B + bias =============
// block = 256 thr = 4 waves; wave computes 32 rows (2 frags) x NT16*16 cols.
// B staged in LDS once per block (contiguous copy), fragments via ds_read_b128.
// A fragment: lane l -> row = l&15, k(i) = 4*(l>>4) + (i&3) + 16*(i>>2) + 32*ks.
// B packed in the SAME k-order -> any hw k-permutation cancels.
// C/D layout (m89-verified): col = lane&15, row = (lane>>4)*4 + reg.
// BLO: include B-lo correction MFMAs (near-fp32 weights). TA=float also splits A.
// STORE: 0 = fp32 out, 1 = bf16 out. MIX: bf16 h residual read-modify-write.
template<int NT16, int NCOLS, int STORE, bool GELU_A, bool MIX, bool BLO, typename TA>
__global__ __launch_bounds__(256, 4) void gemm4(
    const TA* __restrict__ A,
    const ushort_t* __restrict__ Bhi, const ushort_t* __restrict__ Blo,
    const float* __restrict__ bias, void* __restrict__ Cv,
    const float* __restrict__ skip_ptr, int M) {
  constexpr int HN = NT16 * 2048;          // ushorts per (hi) half
  __shared__ ushort_t Bs[HN * (BLO ? 2 : 1)];
  constexpr bool AFP32 = sizeof(TA) == 4;

  for (int i = threadIdx.x; i < (HN / 8) * (BLO ? 2 : 1); i += 256) {
    int half = i / (HN / 8), j = i % (HN / 8);
    const ushort_t* src = (half ? Blo : Bhi) + (size_t)j * 8;
    *(s8v*)&Bs[half * HN + j * 8] = *(const s8v*)src;
  }
  __syncthreads();

  const int lane = threadIdx.x & 63;
  const int wave = threadIdx.x >> 6;
  const int row0 = blockIdx.x * 128 + wave * 32;
  const int g = lane >> 4, li = lane & 15;

  f4v acc0[NT16], acc1[NT16];
#pragma unroll
  for (int ct = 0; ct < NT16; ++ct) {
    acc0[ct] = f4v{0.f, 0.f, 0.f, 0.f};
    acc1[ct] = f4v{0.f, 0.f, 0.f, 0.f};
  }

  int ar0 = row0 + li;       if (ar0 >= M) ar0 = M - 1;
  int ar1 = row0 + 16 + li;  if (ar1 >= M) ar1 = M - 1;

#pragma unroll
  for (int ks = 0; ks < 4; ++ks) {
    s8v ahi[2], alo[2];
#pragma unroll
    for (int rf = 0; rf < 2; ++rf) {
      int ar = rf ? ar1 : ar0;
      if constexpr (AFP32) {
        const float* ap = (const float*)A + (size_t)ar * 128 + ks * 32 + g * 4;
        float4 u0 = *(const float4*)ap;
        float4 u1 = *(const float4*)(ap + 16);
        float x[8] = {u0.x, u0.y, u0.z, u0.w, u1.x, u1.y, u1.z, u1.w};
#pragma unroll
        for (int i = 0; i < 8; ++i) {
          float v = GELU_A ? gelu_f(x[i]) : x[i];
          unsigned short h = f2bf(v);
          ahi[rf][i] = (short)h;
          alo[rf][i] = (short)f2bf(v - bf2f(h));
        }
      } else {
        const ushort_t* ap = (const ushort_t*)A + (size_t)ar * 128 + ks * 32 + g * 4;
        ushort4 u0 = *(const ushort4*)ap;
        ushort4 u1 = *(const ushort4*)(ap + 16);
        ushort_t uu[8] = {u0.x, u0.y, u0.z, u0.w, u1.x, u1.y, u1.z, u1.w};
#pragma unroll
        for (int i = 0; i < 8; ++i) {
          if (GELU_A) ahi[rf][i] = (short)f2bf(gelu_f(bf2f(uu[i])));
          else        ahi[rf][i] = (short)uu[i];
        }
      }
    }
#pragma unroll
    for (int ct = 0; ct < NT16; ++ct) {
      const ushort_t* bp = &Bs[(ct * 4 + ks) * 512 + lane * 8];
      s8v bhi = *(const s8v*)bp;
      acc0[ct] = __builtin_amdgcn_mfma_f32_16x16x32_bf16(ahi[0], bhi, acc0[ct], 0, 0, 0);
      acc1[ct] = __builtin_amdgcn_mfma_f32_16x16x32_bf16(ahi[1], bhi, acc1[ct], 0, 0, 0);
      if constexpr (BLO) {
        s8v blo = *(const s8v*)(bp + HN);
        if constexpr (AFP32) {
          acc0[ct] = __builtin_amdgcn_mfma_f32_16x16x32_bf16(alo[0], bhi, acc0[ct], 0, 0, 0);
          acc1[ct] = __builtin_amdgcn_mfma_f32_16x16x32_bf16(alo[1], bhi, acc1[ct], 0, 0, 0);
        }
        acc0[ct] = __builtin_amdgcn_mfma_f32_16x16x32_bf16(ahi[0], blo, acc0[ct], 0, 0, 0);
        acc1[ct] = __builtin_amdgcn_mfma_f32_16x16x32_bf16(ahi[1], blo, acc1[ct], 0, 0, 0);
      }
    }
  }

  float sskip = 0.f;
  if (MIX) sskip = 1.f / (1.f + __expf(-*skip_ptr));
#pragma unroll
  for (int rf = 0; rf < 2; ++rf) {
#pragma unroll
    for (int ct = 0; ct < NT16; ++ct) {
      int col = ct * 16 + li;
      bool colok = (col < NCOLS);
      float bv = colok ? bias[col] : 0.f;
      f4v a = rf ? acc1[ct] : acc0[ct];
#pragma unroll
      for (int r = 0; r < 4; ++r) {
        int grow = row0 + rf * 16 + g * 4 + r;
        if (grow < M && colok) {
          float v = a[r] + bv;
          size_t off = (size_t)grow * NCOLS + col;
          if constexpr (MIX) {            // bf16 h residual
            ushort_t* Cp = (ushort_t*)Cv;
            float hprev = bf2f(Cp[off]);
            Cp[off] = f2bf(elu_f(sskip * v + (1.f - sskip) * hprev));
          } else if constexpr (STORE == 1) {
            ((ushort_t*)Cv)[off] = f2bf(v);
          } else {
            ((float*)Cv)[off] = v;
          }
        }
      }
    }
  }
}

// ============ KV GEMM: LDS-staged, column-half split, pair-interleaved store ====
// A bf16. grid (GB2, 2); blockIdx.y = column half; per block: 4 K + 4 V tiles
// staged in 32KB LDS (hi only); wave computes 32 rows. Store ushort2{k_c,v_c}
// at kv[row*256 + 2c] -> coalesced, no 64B line shared across blocks.
__global__ __launch_bounds__(256, 4) void gemm_kv(
    const ushort_t* __restrict__ A,
    const ushort_t* __restrict__ Bhi, const ushort_t* __restrict__ Blo,
    const float* __restrict__ bias, ushort_t* __restrict__ kvout, int M) {
  __shared__ ushort_t Bs[16384];           // [kv][t][ks][512]
  const int ch = blockIdx.y;
  for (int i = threadIdx.x; i < 2048; i += 256) {
    int kvh = i >> 10, j = i & 1023;
    const ushort_t* src = Bhi + (size_t)kvh * SLOT_ELEMS + ch * 8192 + j * 8;
    *(s8v*)&Bs[kvh * 8192 + j * 8] = *(const s8v*)src;
  }
  __syncthreads();

  const int lane = threadIdx.x & 63;
  const int wave = threadIdx.x >> 6;
  const int row0 = blockIdx.x * 128 + wave * 32;
  const int g = lane >> 4, li = lane & 15;

  f4v acc0[8], acc1[8];                    // [0..3]=K, [4..7]=V
#pragma unroll
  for (int t = 0; t < 8; ++t) {
    acc0[t] = f4v{0.f, 0.f, 0.f, 0.f};
    acc1[t] = f4v{0.f, 0.f, 0.f, 0.f};
  }

  int ar0 = row0 + li;       if (ar0 >= M) ar0 = M - 1;
  int ar1 = row0 + 16 + li;  if (ar1 >= M) ar1 = M - 1;

#pragma unroll
  for (int ks = 0; ks < 4; ++ks) {
    s8v a0, a1;
    {
      const ushort_t* ap = A + (size_t)ar0 * 128 + ks * 32 + g * 4;
      ushort4 u0 = *(const ushort4*)ap;
      ushort4 u1 = *(const ushort4*)(ap + 16);
      a0[0] = (short)u0.x; a0[1] = (short)u0.y; a0[2] = (short)u0.z; a0[3] = (short)u0.w;
      a0[4] = (short)u1.x; a0[5] = (short)u1.y; a0[6] = (short)u1.z; a0[7] = (short)u1.w;
    }
    {
      const ushort_t* ap = A + (size_t)ar1 * 128 + ks * 32 + g * 4;
      ushort4 u0 = *(const ushort4*)ap;
      ushort4 u1 = *(const ushort4*)(ap + 16);
      a1[0] = (short)u0.x; a1[1] = (short)u0.y; a1[2] = (short)u0.z; a1[3] = (short)u0.w;
      a1[4] = (short)u1.x; a1[5] = (short)u1.y; a1[6] = (short)u1.z; a1[7] = (short)u1.w;
    }
#pragma unroll
    for (int t = 0; t < 4; ++t) {
      s8v kh = *(const s8v*)&Bs[(t * 4 + ks) * 512 + lane * 8];
      acc0[t] = __builtin_amdgcn_mfma_f32_16x16x32_bf16(a0, kh, acc0[t], 0, 0, 0);
      acc1[t] = __builtin_amdgcn_mfma_f32_16x16x32_bf16(a1, kh, acc1[t], 0, 0, 0);
      s8v vh = *(const s8v*)&Bs[8192 + (t * 4 + ks) * 512 + lane * 8];
      acc0[4 + t] = __builtin_amdgcn_mfma_f32_16x16x32_bf16(a0, vh, acc0[4 + t], 0, 0, 0);
      acc1[4 + t] = __builtin_amdgcn_mfma_f32_16x16x32_bf16(a1, vh, acc1[4 + t], 0, 0, 0);
    }
  }

#pragma unroll
  for (int rf = 0; rf < 2; ++rf) {
#pragma unroll
    for (int t = 0; t < 4; ++t) {
      int col = ch * 64 + t * 16 + li;
      float bk = bias[col], bv = bias[128 + col];
#pragma unroll
      for (int r = 0; r < 4; ++r) {
        int grow = row0 + rf * 16 + g * 4 + r;
        if (grow < M) {
          float kvl = rf ? acc1[t][r] : acc0[t][r];
          float vvl = rf ? acc1[4 + t][r] : acc0[4 + t][r];
          ushort2 o;
          o.x = f2bf(kvl + bk);
          o.y = f2bf(vvl + bv);
          *(ushort2*)(kvout + (size_t)grow * 256 + 2 * col) = o;
        }
      }
    }
  }
}

// ------------- combined weights: cw = W @ blockdiag(rel), cb = b @ blockdiag(rel)
__global__ __launch_bounds__(256) void combine_w(
    const float* __restrict__ kqv_w, const float* __restrict__ kqv_b,
    const float* __restrict__ rel_a, const float* __restrict__ rel_m,
    float* __restrict__ cw, float* __restrict__ cb) {
  int b  = blockIdx.x;            // ((l*R)+r)*2+kv
  int kv = b & 1;
  int r  = (b >> 1) % R;
  int l  = b / (2 * R);
  int t_src = (r == 0) ? 0 : 1;
  int i_w   = (kv == 0) ? 0 : 2;
  const float* W    = kqv_w + ((size_t)((l*3 + i_w)*2 + t_src)) * D * D;
  const float* bvec = kqv_b + ((size_t)((l*3 + i_w)*2 + t_src)) * D;
  const float* rel  = ((kv == 0) ? rel_a : rel_m) + ((size_t)(l*R + r)) * H * 32 * 32;
  float* Cout = cw + (size_t)b * D * D;
  float* cbo  = cb + (size_t)b * D;
  for (int idx = threadIdx.x; idx < D * D; idx += 256) {
    int i = idx / D, j = idx % D;
    int h = j >> 5, f = j & 31;
    const float* relh = rel + h * 32 * 32;
    float sum = 0.f;
#pragma unroll
    for (int d = 0; d < 32; ++d) sum += W[i*D + (h*32 + d)] * relh[d*32 + f];
    Cout[idx] = sum;
  }
  if (threadIdx.x < D) {
    int j = threadIdx.x;
    int h = j >> 5, f = j & 31;
    const float* relh = rel + h * 32 * 32;
    float sum = 0.f;
#pragma unroll
    for (int d = 0; d < 32; ++d) sum += bvec[h*32 + d] * relh[d*32 + f];
    cbo[j] = sum;
  }
}

// ------------- pack weight matrices into MFMA-fragment order (hi/lo split) -------
__global__ __launch_bounds__(256) void pack_b(
    const float* __restrict__ proj_w, const float* __restrict__ kqv_w,
    const float* __restrict__ out_w, const float* __restrict__ cls_w,
    const float* __restrict__ cw,
    ushort_t* __restrict__ phi, ushort_t* __restrict__ plo) {
  int slot = blockIdx.x;
  const float* src; int ncol = 128;
  if (slot == 0) src = proj_w;
  else if (slot == 1) src = proj_w + D * D;
  else if (slot == 22) { src = cls_w; ncol = 40; }
  else {
    int l = (slot - 2) / 10, k = (slot - 2) % 10;
    if (k == 0)      src = kqv_w + ((size_t)((l*3 + 1)*2 + 0)) * D * D;
    else if (k == 1) src = kqv_w + ((size_t)((l*3 + 1)*2 + 1)) * D * D;
    else if (k < 8)  { int idx = k - 2; src = cw + ((size_t)((l*R)*2 + idx)) * D * D; }
    else             src = out_w + ((size_t)(l*2 + (k - 8))) * D * D;
  }
  int nt = (ncol + 15) / 16;
  int total = nt * 4 * 512;
  ushort_t* ph = phi + (size_t)slot * SLOT_ELEMS;
  ushort_t* pl = plo + (size_t)slot * SLOT_ELEMS;
  for (int idx = threadIdx.x; idx < total; idx += 256) {
    int j = idx & 7, lane = (idx >> 3) & 63, ks = (idx >> 9) & 3, ct = idx >> 11;
    int k = 4 * (lane >> 4) + (j & 3) + 16 * (j >> 2) + 32 * ks;
    int n = ct * 16 + (lane & 15);
    float v = (n < ncol) ? src[(size_t)k * ncol + n] : 0.f;
    unsigned short h = f2bf(v);
    ph[idx] = h;
    pl[idx] = f2bf(v - bf2f(h));
  }
}

// ---------------- CSR build ----------------
__global__ void count3(const int* __restrict__ ei_w, const int* __restrict__ ei_c,
                       const int* __restrict__ ei_r, int* __restrict__ degz) {
  const int* dst = blockIdx.y == 0 ? ei_w + E : blockIdx.y == 1 ? ei_c + E : ei_r + E;
  int* deg = degz + blockIdx.y * NPP;
  for (int e = blockIdx.x * blockDim.x + threadIdx.x; e < E; e += gridDim.x * blockDim.x)
    atomicAdd(&deg[dst[e]], 1);
}
__global__ void fill3(const int* __restrict__ ei_w, const int* __restrict__ ei_c,
                      const int* __restrict__ ei_r,
                      const int* __restrict__ rp_w, const int* __restrict__ rp_c,
                      const int* __restrict__ rp_r,
                      int* __restrict__ cntz, int* __restrict__ colz) {
  int rel = blockIdx.y;
  const int* ei = rel == 0 ? ei_w : rel == 1 ? ei_c : ei_r;
  const int* dst = ei + E;
  const int* rp  = rel == 0 ? rp_w : rel == 1 ? rp_c : rp_r;
  int* cnt = cntz + rel * NPP;
  int* col = colz + rel * E;
  for (int e = blockIdx.x * blockDim.x + threadIdx.x; e < E; e += gridDim.x * blockDim.x) {
    int d = dst[e];
    int pos = atomicAdd(&cnt[d], 1);
    col[rp[d] + pos] = ei[e];          // store SOURCE node directly
  }
}

// 3-phase exclusive scan over three 100000-length deg arrays (contiguous)
__global__ __launch_bounds__(256) void scan_partial(const int* __restrict__ degz,
                                                    int* __restrict__ bsum) {
  int blk = blockIdx.x, rel = blk / 25, t25 = blk % 25;
  const int* deg = degz + rel * NPP + t25 * 4096;
  int nrem = min(4096, NPP - t25 * 4096);
  int base = threadIdx.x * 16;
  int s = 0;
  if (base < nrem) {
#pragma unroll
    for (int i4 = 0; i4 < 4; ++i4) {
      int4 v = *(const int4*)(deg + base + i4 * 4);
      s += v.x + v.y + v.z + v.w;
    }
  }
  __shared__ int sm[256];
  sm[threadIdx.x] = s; __syncthreads();
  for (int o = 128; o > 0; o >>= 1) {
    if (threadIdx.x < o) sm[threadIdx.x] += sm[threadIdx.x + o];
    __syncthreads();
  }
  if (threadIdx.x == 0) bsum[blk] = sm[0];
}
__global__ __launch_bounds__(128) void scan_offsets(const int* __restrict__ bsum,
                                                    int* __restrict__ boff,
                                                    int* rp_w, int* rp_c, int* rp_r) {
  __shared__ int sm[128];
  int t = threadIdx.x;
  sm[t] = (t < 75) ? bsum[t] : 0;
  __syncthreads();
  for (int o = 1; o < 128; o <<= 1) {
    int v = (t >= o) ? sm[t - o] : 0;
    __syncthreads(); sm[t] += v; __syncthreads();
  }
  if (t < 75) {
    int rel = t / 25;
    int base = rel ? sm[rel * 25 - 1] : 0;
    boff[t] = (t % 25 == 0) ? 0 : (sm[t - 1] - base);
    if (t % 25 == 24) {
      int total = sm[t] - base;
      if (rel == 0) rp_w[NPP] = total;
      else if (rel == 1) rp_c[NPP] = total;
      else rp_r[NA] = total;
    }
  }
}
__global__ __launch_bounds__(256) void scan_final(const int* __restrict__ degz,
                                                  const int* __restrict__ boff,
                                                  int* rp_w, int* rp_c, int* rp_r) {
  int blk = blockIdx.x, rel = blk / 25, t25 = blk % 25;
  const int* deg = degz + rel * NPP + t25 * 4096;
  int* rp = (rel == 0 ? rp_w : rel == 1 ? rp_c : rp_r) + t25 * 4096;
  int nrem = min(4096, NPP - t25 * 4096);
  int base = threadIdx.x * 16;
  bool ok = base < nrem;
  int v[16]; int s = 0;
  if (ok) {
#pragma unroll
    for (int i4 = 0; i4 < 4; ++i4) {
      int4 u = *(const int4*)(deg + base + i4 * 4);
      v[i4*4+0] = u.x; v[i4*4+1] = u.y; v[i4*4+2] = u.z; v[i4*4+3] = u.w;
      s += u.x + u.y + u.z + u.w;
    }
  }
  __shared__ int sm[256];
  sm[threadIdx.x] = s; __syncthreads();
  for (int o = 1; o < 256; o <<= 1) {
    int x = (threadIdx.x >= o) ? sm[threadIdx.x - o] : 0;
    __syncthreads(); sm[threadIdx.x] += x; __syncthreads();
  }
  int run = boff[blk] + sm[threadIdx.x] - s;
  if (ok) {
    int w[16];
#pragma unroll
    for (int i = 0; i < 16; ++i) { w[i] = run; run += v[i]; }
#pragma unroll
    for (int i4 = 0; i4 < 4; ++i4) *(int4*)(rp + base + i4 * 4) = *(const int4*)&w[i4*4];
  }
}

// -------- per-destination attention (no-max softmax: scores are O(1)) -----------
// 1 wave / node; lane holds dims {2l, 2l+1}; head = lane>>4; one ushort4 gather
// per edge from the pair-interleaved kv buffer [k0,v0,k1,v1,...]:
//   u.x=k_{2l}, u.y=v_{2l}, u.z=k_{2l+1}, u.w=v_{2l+1}
// LAST pass writes normalized bf16 aggregate into accb (the q buffer: each wave
// reads its own q row before overwriting it; rows disjoint across waves).
template<int FIRST, int LAST>
__global__ __launch_bounds__(256, 8) void attn3(
    const int* __restrict__ rp, const int* __restrict__ col,
    const ushort_t* __restrict__ q, const ushort_t* __restrict__ kv,
    const float* __restrict__ prel, int ndst,
    float* __restrict__ z_st, float* __restrict__ acc, ushort_t* __restrict__ accb) {
  int dst  = blockIdx.x * 4 + (threadIdx.x >> 6);
  int lane = threadIdx.x & 63;
  if (dst >= ndst) return;
  int head = lane >> 4;
  const float scale = 0.17677669529663688f; // 1/sqrt(32)
  float pr = prel[head] * scale;
  ushort2 qv = *(const ushort2*)(q + (size_t)dst * D + lane * 2);
  float qx = bf2f(qv.x), qy = bf2f(qv.y);
  float z, ax, ay;
  if (FIRST) { z = 0.f; ax = 0.f; ay = 0.f; }
  else {
    z = z_st[dst * H + head];
    float2 a = *(float2*)(acc + (size_t)dst * D + lane * 2);
    ax = a.x; ay = a.y;
  }
  int e0 = rp[dst], e1 = rp[dst + 1];
  int j = e0;
  for (; j + 1 < e1; j += 2) {
    int s0 = col[j], s1 = col[j + 1];
    ushort4 u = *(const ushort4*)(kv + (size_t)s0 * 256 + lane * 4);
    ushort4 w = *(const ushort4*)(kv + (size_t)s1 * 256 + lane * 4);
    float p0 = qx * bf2f(u.x) + qy * bf2f(u.z);
    float p1 = qx * bf2f(w.x) + qy * bf2f(w.z);
    p0 += __shfl_xor(p0, 1); p1 += __shfl_xor(p1, 1);
    p0 += __shfl_xor(p0, 2); p1 += __shfl_xor(p1, 2);
    p0 += __shfl_xor(p0, 4); p1 += __shfl_xor(p1, 4);
    p0 += __shfl_xor(p0, 8); p1 += __shfl_xor(p1, 8);
    float ea = __expf(p0 * pr);
    float eb = __expf(p1 * pr);
    z  += ea + eb;
    ax += ea * bf2f(u.y) + eb * bf2f(w.y);
    ay += ea * bf2f(u.w) + eb * bf2f(w.w);
  }
  if (j < e1) {
    int s0 = col[j];
    ushort4 u = *(const ushort4*)(kv + (size_t)s0 * 256 + lane * 4);
    float p0 = qx * bf2f(u.x) + qy * bf2f(u.z);
    p0 += __shfl_xor(p0, 1);
    p0 += __shfl_xor(p0, 2);
    p0 += __shfl_xor(p0, 4);
    p0 += __shfl_xor(p0, 8);
    float ea = __expf(p0 * pr);
    z  += ea;
    ax += ea * bf2f(u.y);
    ay += ea * bf2f(u.w);
  }
  if (LAST) {
    float inv = 1.f / (z + 1e-16f);
    ushort2 o;
    o.x = f2bf(ax * inv);
    o.y = f2bf(ay * inv);
    *(ushort2*)(accb + (size_t)dst * D + lane * 2) = o;
  } else {
    *(float2*)(acc + (size_t)dst * D + lane * 2) = make_float2(ax, ay);
    if ((lane & 15) == 0) z_st[dst * H + head] = z;
  }
}

extern "C" void kernel_launch(void* const* d_in, const int* in_sizes, int n_in,
                              void* d_out, int out_size, void* d_ws, size_t ws_size,
                              hipStream_t stream) {
  const float* x_a    = (const float*)d_in[0];
  const float* x_p    = (const float*)d_in[1];
  const int*   ei_w   = (const int*)d_in[2];
  const int*   ei_r   = (const int*)d_in[3];
  const int*   ei_c   = (const int*)d_in[4];
  const float* proj_w = (const float*)d_in[5];
  const float* proj_b = (const float*)d_in[6];
  const float* kqv_w  = (const float*)d_in[7];
  const float* kqv_b  = (const float*)d_in[8];
  const float* out_w  = (const float*)d_in[9];
  const float* out_b  = (const float*)d_in[10];
  const float* rel_a  = (const float*)d_in[11];
  const float* rel_m  = (const float*)d_in[12];
  const float* p_rel  = (const float*)d_in[13];
  const float* skip   = (const float*)d_in[14];
  const float* cls_w  = (const float*)d_in[15];
  const float* cls_b  = (const float*)d_in[16];
  float* out = (float*)d_out;

  const size_t NF = (size_t)NA * D;   // 12.8M
  float* ws    = (float*)d_ws;
  // fp32 region first
  float* b_acc = ws;                             // NF (paper attn state)
  float* cw    = b_acc + NF;                     // 12*D*D
  float* cb    = cw + 12 * D * D;                // 12*D
  float* z_st  = cb + 12 * D;                    // NPP*H
  // bf16 region
  ushort_t* h_a  = (ushort_t*)(z_st + (size_t)NPP * H);  // NF
  ushort_t* h_p  = h_a + NF;                             // NF
  ushort_t* b_q  = h_p + NF;                             // NF (q, then bf16 agg)
  ushort_t* b_kv = b_q + NF;                             // 2*NF pair-interleaved
  ushort_t* phi  = b_kv + 2 * NF;                        // 23*SLOT_ELEMS
  ushort_t* plo  = phi + (size_t)NSLOT * SLOT_ELEMS;
  // int region
  int* ip    = (int*)(plo + (size_t)NSLOT * SLOT_ELEMS);
  int* rp_w  = ip;                      // NPP+1
  int* rp_c  = rp_w + (NPP + 1);
  int* rp_r  = rp_c + (NPP + 1);
  int* degz  = rp_r + (NA + 1);         // 3*NPP deg + 3*NPP cnt (contiguous)
  int* cntz  = degz + 3 * NPP;
  int* colz  = cntz + 3 * NPP;          // 3*E (src-node per CSR entry)
  int* bsum  = colz + 3 * E;            // 75
  int* boff  = bsum + 128;              // 75
  size_t need_bytes = (size_t)((char*)(boff + 128) - (char*)d_ws);
  if (ws_size < need_bytes) return;

  hipMemsetAsync(degz, 0, sizeof(int) * 6 * (size_t)NPP, stream);

  count3<<<dim3(256, 3), 256, 0, stream>>>(ei_w, ei_c, ei_r, degz);
  scan_partial<<<75, 256, 0, stream>>>(degz, bsum);
  scan_offsets<<<1, 128, 0, stream>>>(bsum, boff, rp_w, rp_c, rp_r);
  scan_final<<<75, 256, 0, stream>>>(degz, boff, rp_w, rp_c, rp_r);
  fill3<<<dim3(256, 3), 256, 0, stream>>>(ei_w, ei_c, ei_r, rp_w, rp_c, rp_r, cntz, colz);
  int* col_w = colz;
  int* col_c = colz + E;
  int* col_r = colz + 2 * E;

  combine_w<<<12, 256, 0, stream>>>(kqv_w, kqv_b, rel_a, rel_m, cw, cb);
  pack_b<<<NSLOT, 256, 0, stream>>>(proj_w, kqv_w, out_w, cls_w, cw, phi, plo);

  auto PH = [&](int s){ return phi + (size_t)s * SLOT_ELEMS; };
  auto PL = [&](int s){ return plo + (size_t)s * SLOT_ELEMS; };

  const int GB2 = (NA + 127) / 128;    // 782
  const dim3 G1(GB2, 1), GKV(GB2, 2);
  // initial projections (fp32 input, bf16 h out, A+B split for precision)
  gemm4<8, 128, 1, false, false, true, float><<<G1, 256, 0, stream>>>(
      x_a, PH(0), PL(0), proj_b,     h_a, nullptr, NA);
  gemm4<8, 128, 1, false, false, true, float><<<G1, 256, 0, stream>>>(
      x_p, PH(1), PL(1), proj_b + D, h_p, nullptr, NPP);

  for (int l = 0; l < L; ++l) {
    const int SQA = 2 + l * 10 + 0, SQP = 2 + l * 10 + 1;
    auto SKV = [&](int r){ return 2 + l * 10 + 2 + r * 2; };  // k slot; v slot = +1
    const int SO0 = 2 + l * 10 + 8, SO1 = 2 + l * 10 + 9;
    const float* bq_a = kqv_b + ((size_t)((l*3 + 1)*2 + 0)) * D;
    const float* bq_p = kqv_b + ((size_t)((l*3 + 1)*2 + 1)) * D;
    auto CB2 = [&](int r){ return cb + ((size_t)((l*R + r)*2)) * D; };  // 256 floats (k|v)

    // ---- author destination (rev_writes r=1, src=paper) ----
    gemm4<8, 128, 1, false, false, false, ushort_t><<<G1, 256, 0, stream>>>(
        h_a, PH(SQA), PL(SQA), bq_a, b_q, nullptr, NA);
    gemm_kv<<<GKV, 256, 0, stream>>>(
        h_p, PH(SKV(1)), PL(SKV(1)), CB2(1), b_kv, NPP);
    attn3<1, 1><<<(NA + 3) / 4, 256, 0, stream>>>(
        rp_r, col_r, b_q, b_kv, p_rel + (size_t)(l*R + 1) * H, NA, z_st, b_acc, b_q);
    // writes-relation K/V from OLD h_a (before author update)
    gemm_kv<<<GKV, 256, 0, stream>>>(
        h_a, PH(SKV(0)), PL(SKV(0)), CB2(0), b_kv, NA);
    // author out-mix (in-place bf16 h_a); A = bf16 agg in b_q, gelu applied
    gemm4<8, 128, 1, true, true, false, ushort_t><<<G1, 256, 0, stream>>>(
        b_q, PH(SO0), PL(SO0), out_b + (size_t)(l*2 + 0) * D, h_a,
        skip + l*2 + 0, NA);

    // ---- paper destination: joint softmax over writes(r=0) + cites(r=2) ----
    gemm4<8, 128, 1, false, false, false, ushort_t><<<G1, 256, 0, stream>>>(
        h_p, PH(SQP), PL(SQP), bq_p, b_q, nullptr, NPP);
    attn3<1, 0><<<(NPP + 3) / 4, 256, 0, stream>>>(
        rp_w, col_w, b_q, b_kv, p_rel + (size_t)(l*R + 0) * H, NPP, z_st, b_acc, b_q);
    gemm_kv<<<GKV, 256, 0, stream>>>(
        h_p, PH(SKV(2)), PL(SKV(2)), CB2(2), b_kv, NPP);
    attn3<0, 1><<<(NPP + 3) / 4, 256, 0, stream>>>(
        rp_c, col_c, b_q, b_kv, p_rel + (size_t)(l*R + 2) * H, NPP, z_st, b_acc, b_q);
    gemm4<8, 128, 1, true, true, false, ushort_t><<<G1, 256, 0, stream>>>(
        b_q, PH(SO1), PL(SO1), out_b + (size_t)(l*2 + 1) * D, h_p,
        skip + l*2 + 1, NPP);
  }

  gemm4<3, 40, 0, false, false, true, ushort_t><<<G1, 256, 0, stream>>>(
      h_p, PH(22), PL(22), cls_b, out, nullptr, NPP);
}